// Round 4
// baseline (327.101 us; speedup 1.0000x reference)
//
#include <hip/hip_runtime.h>
#include <hip/hip_bf16.h>
#include <math.h>

#define HW 2304
#define EPSV 1e-5f
// ATT_SCALE * log2(e): softmax runs in exp2 domain
#define QS_LOG2E (0.17677669529663687f * 1.44269504088896340f)

enum { E_CV1 = 0, E_QKV = 1, E_PROJ = 2, E_F1 = 3, E_F2 = 4, E_CV2 = 5 };

typedef __attribute__((ext_vector_type(8))) short bf16x8;
typedef __attribute__((ext_vector_type(4))) float f32x4;

static __device__ __forceinline__ ushort b16(float f) {
    union { __hip_bfloat16 h; ushort u; } cv;
    cv.h = __float2bfloat16(f);
    return cv.u;
}

// ---- weights fp32 -> bf16 (concatenated) ----
__global__ __launch_bounds__(256) void cvt_w(
    const float* __restrict__ w0, const float* __restrict__ w1,
    const float* __restrict__ w2, const float* __restrict__ w3,
    const float* __restrict__ w4, const float* __restrict__ w5,
    ushort* __restrict__ WB)
{
    const int idx = (blockIdx.x * 256 + threadIdx.x) * 4;  // < 458752
    const float* src;
    int off;
    if      (idx < 65536)  { src = w0; off = 0; }
    else if (idx < 163840) { src = w1; off = 65536; }
    else if (idx < 196608) { src = w2; off = 163840; }
    else if (idx < 262144) { src = w3; off = 196608; }
    else if (idx < 327680) { src = w4; off = 262144; }
    else                   { src = w5; off = 327680; }
    float4 v = *(const float4*)&src[idx - off];
    ushort4 u;
    u.x = b16(v.x); u.y = b16(v.y); u.z = b16(v.z); u.w = b16(v.w);
    *(ushort4*)&WB[idx] = u;
}

// ---- x fp32 [3][256][HW] -> bf16 [3][HW][256] ----
__global__ __launch_bounds__(256) void txp_x(
    const float* __restrict__ X, ushort* __restrict__ XT)
{
    #pragma unroll
    for (int k = 0; k < 4; k++) {
        const int Q = blockIdx.x * 1024 + k * 256 + threadIdx.x;  // < 442368
        const int b = Q / 147456;
        const int r = Q - b * 147456;
        const int c = r / 576;
        const int n = (r - c * 576) * 4;
        float4 v = *(const float4*)&X[(size_t)(b * 256 + c) * HW + n];
        XT[((size_t)b * HW + n + 0) * 256 + c] = b16(v.x);
        XT[((size_t)b * HW + n + 1) * 256 + c] = b16(v.y);
        XT[((size_t)b * HW + n + 2) * 256 + c] = b16(v.z);
        XT[((size_t)b * HW + n + 3) * 256 + c] = b16(v.w);
    }
}

// ---- MFMA GEMM: D[o][n] = sum_c W[o][c] * XT[n][c], per batch b ----
// grid (18, O/128, 3); 256 threads = 4 waves; wave tile 64o x 64n.
// E_QKV: batch 0 -> QT (scaled), batch 1 -> KT, batch 2 -> VB channel-major.
template <int EPI>
__global__ __launch_bounds__(256) void gemm_mfma(
    const ushort* __restrict__ W, const ushort* __restrict__ XT, int K,
    long syb,
    const float* __restrict__ q0, const float* __restrict__ q1,
    const float* __restrict__ q2, const float* __restrict__ q3,
    const float* __restrict__ R, float* __restrict__ Yf,
    ushort* __restrict__ U0, ushort* __restrict__ U1, ushort* __restrict__ U2,
    int uoff)
{
    const int b = blockIdx.z;
    const int t = threadIdx.x;
    const int w = t >> 6, l = t & 63;
    const int ln = l & 15, lg = l >> 4;
    const int wo = (w & 1) * 64, wn = (w >> 1) * 64;
    const int ob = blockIdx.y * 128 + wo;
    const int nb = blockIdx.x * 128 + wn;

    const ushort* ap = W + (size_t)(ob + ln) * K + lg * 8;
    const ushort* bp = XT + ((size_t)b * HW + nb + ln) * K + lg * 8;

    bf16x8 a0[4], bb0[4], a1[4], bb1[4];
    #pragma unroll
    for (int i = 0; i < 4; i++) {
        a0[i]  = *(const bf16x8*)(ap + (size_t)i * 16 * K);
        bb0[i] = *(const bf16x8*)(bp + (size_t)i * 16 * K);
    }
    f32x4 acc[4][4];
    #pragma unroll
    for (int i = 0; i < 4; i++)
        #pragma unroll
        for (int j = 0; j < 4; j++) acc[i][j] = (f32x4){0.f, 0.f, 0.f, 0.f};

    for (int c0 = 32; c0 <= K; c0 += 32) {
        if (c0 < K) {
            #pragma unroll
            for (int i = 0; i < 4; i++) {
                a1[i]  = *(const bf16x8*)(ap + (size_t)i * 16 * K + c0);
                bb1[i] = *(const bf16x8*)(bp + (size_t)i * 16 * K + c0);
            }
        }
        #pragma unroll
        for (int i = 0; i < 4; i++)
            #pragma unroll
            for (int j = 0; j < 4; j++)
                acc[i][j] = __builtin_amdgcn_mfma_f32_16x16x32_bf16(a0[i], bb0[j], acc[i][j], 0, 0, 0);
        #pragma unroll
        for (int i = 0; i < 4; i++) { a0[i] = a1[i]; bb0[i] = bb1[i]; }
    }

    #pragma unroll
    for (int i = 0; i < 4; i++) {
        const int obase = ob + i * 16 + lg * 4;   // 4 consecutive o (r=0..3)
        if (EPI == E_CV1 || EPI == E_CV2) {
            float sc[4], sh[4];
            #pragma unroll
            for (int r = 0; r < 4; r++) {
                const int o = obase + r;
                const float rs = rsqrtf(q3[o] + EPSV);
                sc[r] = q0[o] * rs;
                sh[r] = q1[o] - q2[o] * sc[r];
            }
            #pragma unroll
            for (int j = 0; j < 4; j++) {
                const int n = nb + j * 16 + ln;
                ushort4 u;
                #pragma unroll
                for (int r = 0; r < 4; r++) {
                    float y = fmaf(acc[i][j][r], sc[r], sh[r]);
                    y = y / (1.f + __expf(-y));
                    Yf[(size_t)b * syb + (size_t)(obase + r) * HW + n] = y;
                    if (EPI == E_CV1) {
                        if (r == 0) u.x = b16(y); else if (r == 1) u.y = b16(y);
                        else if (r == 2) u.z = b16(y); else u.w = b16(y);
                    }
                }
                if (EPI == E_CV1)
                    *(ushort4*)&U0[((size_t)b * HW + n) * 512 + obase] = u;
            }
        } else if (EPI == E_QKV) {
            // Reference quirk: Q = batch0's full 384ch, K = batch1's, V = batch2's.
            const int gh = obase >> 5;   // (chunk*4 + head), 0..11
            const int d0 = obase & 31;
            float bias[4];
            #pragma unroll
            for (int r = 0; r < 4; r++) bias[r] = q0[obase + r];
            #pragma unroll
            for (int j = 0; j < 4; j++) {
                const int n = nb + j * 16 + ln;
                if (b == 0) {
                    ushort4 u;
                    u.x = b16((acc[i][j][0] + bias[0]) * QS_LOG2E);
                    u.y = b16((acc[i][j][1] + bias[1]) * QS_LOG2E);
                    u.z = b16((acc[i][j][2] + bias[2]) * QS_LOG2E);
                    u.w = b16((acc[i][j][3] + bias[3]) * QS_LOG2E);
                    *(ushort4*)&U0[((size_t)gh * HW + n) * 32 + d0] = u;
                } else if (b == 1) {
                    ushort4 u;
                    u.x = b16(acc[i][j][0] + bias[0]);
                    u.y = b16(acc[i][j][1] + bias[1]);
                    u.z = b16(acc[i][j][2] + bias[2]);
                    u.w = b16(acc[i][j][3] + bias[3]);
                    *(ushort4*)&U1[((size_t)gh * HW + n) * 32 + d0] = u;
                } else {
                    #pragma unroll
                    for (int r = 0; r < 4; r++)
                        U2[(size_t)(obase + r) * HW + n] = b16(acc[i][j][r] + bias[r]);
                }
            }
        } else if (EPI == E_PROJ || EPI == E_F2) {
            #pragma unroll
            for (int j = 0; j < 4; j++) {
                const int n = nb + j * 16 + ln;
                ushort4 u;
                #pragma unroll
                for (int r = 0; r < 4; r++) {
                    const int o = obase + r;
                    float y = acc[i][j][r] + q0[o]
                            + R[(size_t)b * syb + (size_t)o * HW + n];
                    Yf[(size_t)b * syb + (size_t)o * HW + n] = y;
                    if (EPI == E_F2) {
                        if (r == 0) u.x = b16(y); else if (r == 1) u.y = b16(y);
                        else if (r == 2) u.z = b16(y); else u.w = b16(y);
                    }
                }
                if (EPI == E_F2)
                    *(ushort4*)&U0[((size_t)b * HW + n) * 512 + uoff + obase] = u;
            }
        } else {  // E_F1: gelu -> FT bf16 [n][256]
            float bias[4];
            #pragma unroll
            for (int r = 0; r < 4; r++) bias[r] = q0[obase + r];
            #pragma unroll
            for (int j = 0; j < 4; j++) {
                const int n = nb + j * 16 + ln;
                ushort4 u;
                #pragma unroll
                for (int r = 0; r < 4; r++) {
                    float y = acc[i][j][r] + bias[r];
                    y = 0.5f * y * (1.f + erff(y * 0.70710678f));
                    if (r == 0) u.x = b16(y); else if (r == 1) u.y = b16(y);
                    else if (r == 2) u.z = b16(y); else u.w = b16(y);
                }
                *(ushort4*)&U0[((size_t)b * HW + n) * 256 + obase] = u;
            }
        }
    }
}

// ---- GroupNorm stats (fp32 CAT) ----
__global__ __launch_bounds__(256) void gn_partial(
    const float* __restrict__ X, long sxb, float* __restrict__ stats)
{
    const int b = blockIdx.y;
    const float* xb = X + (size_t)b * sxb + (size_t)blockIdx.x * 6144;
    float s = 0.f, sq = 0.f;
    #pragma unroll
    for (int k = 0; k < 6; k++) {
        float4 v = *(const float4*)&xb[(size_t)(k * 256 + threadIdx.x) * 4];
        s  += v.x + v.y + v.z + v.w;
        sq += v.x * v.x + v.y * v.y + v.z * v.z + v.w * v.w;
    }
    #pragma unroll
    for (int off = 32; off; off >>= 1) { s += __shfl_xor(s, off); sq += __shfl_xor(sq, off); }
    __shared__ float ps[4], pq[4];
    const int wave = threadIdx.x >> 6, lane = threadIdx.x & 63;
    if (lane == 0) { ps[wave] = s; pq[wave] = sq; }
    __syncthreads();
    if (threadIdx.x == 0) {
        stats[b * 48 + blockIdx.x]       = ps[0] + ps[1] + ps[2] + ps[3];
        stats[144 + b * 48 + blockIdx.x] = pq[0] + pq[1] + pq[2] + pq[3];
    }
}

__global__ void gn_reduce(float* __restrict__ stats)
{
    const int b = blockIdx.x, t = threadIdx.x;
    float s  = (t < 48) ? stats[b * 48 + t] : 0.f;
    float sq = (t < 48) ? stats[144 + b * 48 + t] : 0.f;
    #pragma unroll
    for (int off = 32; off; off >>= 1) { s += __shfl_xor(s, off); sq += __shfl_xor(sq, off); }
    if (t == 0) {
        const float inv = 1.f / 294912.f;
        const float mean = s * inv;
        const float var  = sq * inv - mean * mean;
        stats[288 + b] = mean;
        stats[292 + b] = rsqrtf(var + EPSV);
    }
}

// ---- GN apply -> ZT bf16 [b][n][128] ----
__global__ __launch_bounds__(256) void gn_apply_t(
    const float* __restrict__ X, long sxb, ushort* __restrict__ ZT,
    const float* __restrict__ g, const float* __restrict__ bb,
    const float* __restrict__ stats)
{
    const int b = blockIdx.y;
    const float mean = stats[288 + b];
    const float rs   = stats[292 + b];
    const float* xb = X + (size_t)b * sxb;
    #pragma unroll
    for (int k = 0; k < 4; k++) {
        const int v4 = blockIdx.x * 1024 + k * 256 + threadIdx.x;
        const int c  = v4 / 576;
        const int n  = (v4 - c * 576) * 4;
        const float sc = rs * g[c];
        const float sh = bb[c] - mean * sc;
        float4 v = *(const float4*)&xb[(size_t)v4 * 4];
        ZT[((size_t)b * HW + n + 0) * 128 + c] = b16(fmaf(v.x, sc, sh));
        ZT[((size_t)b * HW + n + 1) * 128 + c] = b16(fmaf(v.y, sc, sh));
        ZT[((size_t)b * HW + n + 2) * 128 + c] = b16(fmaf(v.z, sc, sh));
        ZT[((size_t)b * HW + n + 3) * 128 + c] = b16(fmaf(v.w, sc, sh));
    }
}

// ---- MFMA flash attention, split-K=2, exp2 domain, un-normalized partials ----
// grid (36, 12, 2); 256 threads = 4 independent waves, each 16 queries.
__global__ __launch_bounds__(256) void attn_mfma(
    const ushort* __restrict__ QT,  // [12][HW][32] bf16, pre-scaled by QS_LOG2E
    const ushort* __restrict__ KT,  // [12][HW][32] bf16
    const ushort* __restrict__ VB,  // [384][HW] bf16 (batch2 channels, natural order)
    float* __restrict__ PO0, float* __restrict__ PO1,
    float* __restrict__ MS)         // [2][12][HW][2]
{
    __shared__ __align__(16) ushort plds[4][16][72];
    const int gh = blockIdx.y, g = gh >> 2, h = gh & 3;
    const int half = blockIdx.z;
    const int t = threadIdx.x, w = t >> 6, l = t & 63;
    const int ln = l & 15, lg = l >> 4;
    const int n0 = (blockIdx.x * 4 + w) * 16;
    const int ms0 = half * 1152, mend = ms0 + 1152;

    const bf16x8 qf = *(const bf16x8*)(QT + ((size_t)gh * HW + n0 + ln) * 32 + lg * 8);

    const ushort* ktp = KT + (size_t)gh * HW * 32 + ln * 32 + lg * 8;     // + m*32
    const ushort* vp0 = VB + ((size_t)g * 128 + h * 32 + ln) * HW + lg * 8;
    const ushort* vp1 = vp0 + (size_t)16 * HW;

    f32x4 o0 = {0.f, 0.f, 0.f, 0.f}, o1 = {0.f, 0.f, 0.f, 0.f};
    float M = -3.0e38f, S = 0.f;

    bf16x8 kf[4], vf[4], kfn[4], vfn[4];
    #pragma unroll
    for (int mc = 0; mc < 4; mc++) kf[mc] = *(const bf16x8*)(ktp + (size_t)(ms0 + mc * 16) * 32);
    vf[0] = *(const bf16x8*)(vp0 + ms0);      vf[1] = *(const bf16x8*)(vp0 + ms0 + 32);
    vf[2] = *(const bf16x8*)(vp1 + ms0);      vf[3] = *(const bf16x8*)(vp1 + ms0 + 32);

    for (int m0 = ms0; m0 < mend; m0 += 64) {
        f32x4 st[4];
        const f32x4 zero = {0.f, 0.f, 0.f, 0.f};
        #pragma unroll
        for (int mc = 0; mc < 4; mc++)
            st[mc] = __builtin_amdgcn_mfma_f32_16x16x32_bf16(kf[mc], qf, zero, 0, 0, 0);

        if (m0 + 64 < mend) {
            #pragma unroll
            for (int mc = 0; mc < 4; mc++)
                kfn[mc] = *(const bf16x8*)(ktp + (size_t)(m0 + 64 + mc * 16) * 32);
            vfn[0] = *(const bf16x8*)(vp0 + m0 + 64);  vfn[1] = *(const bf16x8*)(vp0 + m0 + 96);
            vfn[2] = *(const bf16x8*)(vp1 + m0 + 64);  vfn[3] = *(const bf16x8*)(vp1 + m0 + 96);
        }

        float mx = st[0][0];
        #pragma unroll
        for (int mc = 0; mc < 4; mc++)
            #pragma unroll
            for (int r = 0; r < 4; r++) mx = fmaxf(mx, st[mc][r]);
        mx = fmaxf(mx, __shfl_xor(mx, 16));
        mx = fmaxf(mx, __shfl_xor(mx, 32));
        const float Mn = fmaxf(M, mx);
        const float corr = exp2f(M - Mn);
        float ps = 0.f;
        ushort4 pw[4];
        #pragma unroll
        for (int mc = 0; mc < 4; mc++) {
            float p0v = exp2f(st[mc][0] - Mn), p1v = exp2f(st[mc][1] - Mn);
            float p2v = exp2f(st[mc][2] - Mn), p3v = exp2f(st[mc][3] - Mn);
            ps += (p0v + p1v) + (p2v + p3v);
            pw[mc].x = b16(p0v); pw[mc].y = b16(p1v);
            pw[mc].z = b16(p2v); pw[mc].w = b16(p3v);
        }
        ps += __shfl_xor(ps, 16);
        ps += __shfl_xor(ps, 32);
        S = S * corr + ps;
        M = Mn;
        #pragma unroll
        for (int r = 0; r < 4; r++) { o0[r] *= corr; o1[r] *= corr; }

        #pragma unroll
        for (int mc = 0; mc < 4; mc++)
            *(ushort4*)&plds[w][ln][mc * 16 + lg * 4] = pw[mc];
        bf16x8 pf0 = *(const bf16x8*)&plds[w][ln][lg * 8];
        bf16x8 pf1 = *(const bf16x8*)&plds[w][ln][32 + lg * 8];

        o0 = __builtin_amdgcn_mfma_f32_16x16x32_bf16(vf[0], pf0, o0, 0, 0, 0);
        o0 = __builtin_amdgcn_mfma_f32_16x16x32_bf16(vf[1], pf1, o0, 0, 0, 0);
        o1 = __builtin_amdgcn_mfma_f32_16x16x32_bf16(vf[2], pf0, o1, 0, 0, 0);
        o1 = __builtin_amdgcn_mfma_f32_16x16x32_bf16(vf[3], pf1, o1, 0, 0, 0);

        #pragma unroll
        for (int mc = 0; mc < 4; mc++) { kf[mc] = kfn[mc]; vf[mc] = vfn[mc]; }
    }

    float* po = half ? PO1 : PO0;
    #pragma unroll
    for (int r = 0; r < 4; r++) {
        const int d = lg * 4 + r;
        po[((size_t)gh * 32 + d) * HW + n0 + ln]      = o0[r];
        po[((size_t)gh * 32 + d + 16) * HW + n0 + ln] = o1[r];
    }
    if (lg == 0) {
        float* ms = MS + (((size_t)half * 12 + gh) * HW + n0 + ln) * 2;
        ms[0] = M; ms[1] = S;
    }
}

// ---- merge split-K partials -> AOT bf16 [g][n][128] (channel = d*4+h) ----
__global__ __launch_bounds__(256) void attn_merge(
    const float* __restrict__ PO0, const float* __restrict__ PO1,
    const float* __restrict__ MS, ushort* __restrict__ AOT)
{
    const int flat = blockIdx.x * 256 + threadIdx.x;  // < 27648
    const int gh = flat / HW, n = flat % HW;
    const float M0 = MS[((size_t)gh * HW + n) * 2 + 0];
    const float S0 = MS[((size_t)gh * HW + n) * 2 + 1];
    const float M1 = MS[(((size_t)12 + gh) * HW + n) * 2 + 0];
    const float S1 = MS[(((size_t)12 + gh) * HW + n) * 2 + 1];
    const float M = fmaxf(M0, M1);
    float w0 = exp2f(M0 - M), w1 = exp2f(M1 - M);
    const float inv = 1.f / (S0 * w0 + S1 * w1);
    w0 *= inv; w1 *= inv;
    const int g = gh >> 2, h = gh & 3;
    ushort* dst = AOT + ((size_t)g * HW + n) * 128 + h;
    const float* p0 = PO0 + (size_t)gh * 32 * HW + n;
    const float* p1 = PO1 + (size_t)gh * 32 * HW + n;
    #pragma unroll
    for (int d = 0; d < 32; d++)
        dst[d * 4] = b16(p0[(size_t)d * HW] * w0 + p1[(size_t)d * HW] * w1);
}

extern "C" void kernel_launch(void* const* d_in, const int* in_sizes, int n_in,
                              void* d_out, int out_size, void* d_ws, size_t ws_size,
                              hipStream_t stream)
{
    (void)in_sizes; (void)n_in; (void)out_size; (void)ws_size;
    const float* x      = (const float*)d_in[0];
    const float* cv1_w  = (const float*)d_in[1];
    const float* cv1_g  = (const float*)d_in[2];
    const float* cv1_b  = (const float*)d_in[3];
    const float* cv1_m  = (const float*)d_in[4];
    const float* cv1_v  = (const float*)d_in[5];
    const float* n1_g   = (const float*)d_in[6];
    const float* n1_b   = (const float*)d_in[7];
    const float* qkv_w  = (const float*)d_in[8];
    const float* qkv_b  = (const float*)d_in[9];
    const float* proj_w = (const float*)d_in[10];
    const float* proj_b = (const float*)d_in[11];
    const float* n2_g   = (const float*)d_in[12];
    const float* n2_b   = (const float*)d_in[13];
    const float* f1_w   = (const float*)d_in[14];
    const float* f1_b   = (const float*)d_in[15];
    const float* f2_w   = (const float*)d_in[16];
    const float* f2_b   = (const float*)d_in[17];
    const float* cv2_w  = (const float*)d_in[18];
    const float* cv2_g  = (const float*)d_in[19];
    const float* cv2_b  = (const float*)d_in[20];
    const float* cv2_m  = (const float*)d_in[21];
    const float* cv2_v  = (const float*)d_in[22];
    float* out = (float*)d_out;

    float* ws = (float*)d_ws;
    float*  CAT  = ws;                               // 3x512xHW fp32
    ushort* CATT = (ushort*)(ws + 3538944);          // [3][HW][512] bf16
    ushort* ZT   = (ushort*)(ws + 5308416);          // [3][HW][128] bf16
    ushort* QT   = (ushort*)(ws + 5750784);          // [12][HW][32] bf16
    ushort* KTb  = (ushort*)(ws + 6193152);          // [12][HW][32] bf16
    ushort* VB   = (ushort*)(ws + 6635520);          // [384][HW] bf16
    ushort* FT   = QT;                               // [3][HW][256] bf16 (alias, disjoint)
    float*  MS   = ws + 7077888;                     // [2][12][HW][2]
    ushort* AOT  = (ushort*)(ws + 7188480);          // [3][HW][128] bf16
    ushort* WB   = (ushort*)(ws + 7630848);          // 458752 bf16 weights
    float*  STAT = ws + 7860224;                     // 512
    // d_out doubles as scratch (fully rewritten each call):
    ushort* XTX  = (ushort*)d_out;                   // [3][HW][256] bf16 (dead after cv1)
    float*  PO0  = (float*)d_out;                    // [12][32][HW] fp32 (attention)
    float*  PO1  = PO0 + 884736;

    const long sCAT = 512L * HW, sOUT = 256L * HW;
    dim3 blk(256);

    cvt_w<<<dim3(448), blk, 0, stream>>>(cv1_w, qkv_w, proj_w, f1_w, f2_w, cv2_w, WB);
    txp_x<<<dim3(432), blk, 0, stream>>>(x, XTX);

    // cv1: 256ch <- 256ch, BN+SiLU -> CAT rows 0..255 (fp32) + CATT cols 0..255
    gemm_mfma<E_CV1><<<dim3(18, 2, 3), blk, 0, stream>>>(
        WB + 0, XTX, 256, sCAT, cv1_g, cv1_b, cv1_m, cv1_v,
        nullptr, CAT, CATT, nullptr, nullptr, 0);

    for (int i = 0; i < 2; i++) {
        const long prev = (i == 0) ? 128L : 256L;
        const long next = 256L + 128L * i;

        gn_partial<<<dim3(48, 3), blk, 0, stream>>>(CAT + prev * HW, sCAT, STAT);
        gn_reduce<<<dim3(3), dim3(64), 0, stream>>>(STAT);
        gn_apply_t<<<dim3(72, 3), blk, 0, stream>>>(CAT + prev * HW, sCAT, ZT,
                                                    n1_g + i * 128, n1_b + i * 128, STAT);
        gemm_mfma<E_QKV><<<dim3(18, 3, 3), blk, 0, stream>>>(
            WB + 65536 + (size_t)i * 49152, ZT, 128, 0, qkv_b + i * 384,
            nullptr, nullptr, nullptr, nullptr, nullptr, QT, KTb, VB, 0);
        attn_mfma<<<dim3(36, 12, 2), blk, 0, stream>>>(QT, KTb, VB, PO0, PO1, MS);
        attn_merge<<<dim3(108), blk, 0, stream>>>(PO0, PO1, MS, AOT);
        gemm_mfma<E_PROJ><<<dim3(18, 1, 3), blk, 0, stream>>>(
            WB + 163840 + (size_t)i * 16384, AOT, 128, sCAT, proj_b + i * 128,
            nullptr, nullptr, nullptr, CAT + prev * HW, CAT + next * HW,
            nullptr, nullptr, nullptr, 0);

        gn_partial<<<dim3(48, 3), blk, 0, stream>>>(CAT + next * HW, sCAT, STAT);
        gn_reduce<<<dim3(3), dim3(64), 0, stream>>>(STAT);
        gn_apply_t<<<dim3(72, 3), blk, 0, stream>>>(CAT + next * HW, sCAT, ZT,
                                                    n2_g + i * 128, n2_b + i * 128, STAT);
        gemm_mfma<E_F1><<<dim3(18, 2, 3), blk, 0, stream>>>(
            WB + 196608 + (size_t)i * 32768, ZT, 128, 0, f1_b + i * 256,
            nullptr, nullptr, nullptr, nullptr, nullptr, FT, nullptr, nullptr, 0);
        gemm_mfma<E_F2><<<dim3(18, 1, 3), blk, 0, stream>>>(
            WB + 262144 + (size_t)i * 32768, FT, 256, sCAT, f2_b + i * 128,
            nullptr, nullptr, nullptr, CAT + next * HW, CAT + next * HW,
            CATT, nullptr, nullptr, (int)next);
    }

    // cv2: 256ch <- 512ch concat, BN+SiLU -> out
    gemm_mfma<E_CV2><<<dim3(18, 2, 3), blk, 0, stream>>>(
        WB + 327680, CATT, 512, sOUT, cv2_g, cv2_b, cv2_m, cv2_v,
        nullptr, out, nullptr, nullptr, nullptr, 0);
}

// Round 5
// 245.997 us; speedup vs baseline: 1.3297x; 1.3297x over previous
//
#include <hip/hip_runtime.h>
#include <hip/hip_bf16.h>
#include <math.h>

#define HW 2304
#define EPSV 1e-5f
// ATT_SCALE * log2(e): softmax runs in exp2 domain
#define QS_LOG2E (0.17677669529663687f * 1.44269504088896340f)

enum { E_CV1 = 0, E_QKV = 1, E_PROJ = 2, E_F1 = 3, E_F2 = 4, E_CV2 = 5 };

typedef __attribute__((ext_vector_type(8))) short bf16x8;
typedef __attribute__((ext_vector_type(4))) float f32x4;
typedef __attribute__((ext_vector_type(2))) unsigned long long u64x2;

static __device__ __forceinline__ ushort b16(float f) {
    union { __hip_bfloat16 h; ushort u; } cv;
    cv.h = __float2bfloat16(f);
    return cv.u;
}

// ---- weights fp32 -> bf16 (concatenated) ----
__global__ __launch_bounds__(256) void cvt_w(
    const float* __restrict__ w0, const float* __restrict__ w1,
    const float* __restrict__ w2, const float* __restrict__ w3,
    const float* __restrict__ w4, const float* __restrict__ w5,
    ushort* __restrict__ WB)
{
    const int idx = (blockIdx.x * 256 + threadIdx.x) * 4;  // < 458752
    const float* src;
    int off;
    if      (idx < 65536)  { src = w0; off = 0; }
    else if (idx < 163840) { src = w1; off = 65536; }
    else if (idx < 196608) { src = w2; off = 163840; }
    else if (idx < 262144) { src = w3; off = 196608; }
    else if (idx < 327680) { src = w4; off = 262144; }
    else                   { src = w5; off = 327680; }
    float4 v = *(const float4*)&src[idx - off];
    ushort4 u;
    u.x = b16(v.x); u.y = b16(v.y); u.z = b16(v.z); u.w = b16(v.w);
    *(ushort4*)&WB[idx] = u;
}

// ---- x fp32 [3][256][HW] -> bf16 [3][HW][256], LDS transpose, coalesced ----
__global__ __launch_bounds__(256) void txp_x(
    const float* __restrict__ X, ushort* __restrict__ XT)
{
    __shared__ ushort tb[64][68];
    const int b = blockIdx.z, cb = blockIdx.y * 64, nb = blockIdx.x * 64;
    const int t = threadIdx.x;
    #pragma unroll
    for (int k = 0; k < 4; k++) {
        const int row = k * 16 + (t >> 4), cq = t & 15;
        float4 v = *(const float4*)&X[(size_t)(b * 256 + cb + row) * HW + nb + cq * 4];
        ushort4 u; u.x = b16(v.x); u.y = b16(v.y); u.z = b16(v.z); u.w = b16(v.w);
        *(ushort4*)&tb[row][cq * 4] = u;
    }
    __syncthreads();
    #pragma unroll
    for (int k = 0; k < 4; k++) {
        const int n = k * 16 + (t >> 4), cq = t & 15;
        ushort4 u;
        u.x = tb[cq * 4 + 0][n]; u.y = tb[cq * 4 + 1][n];
        u.z = tb[cq * 4 + 2][n]; u.w = tb[cq * 4 + 3][n];
        *(ushort4*)&XT[((size_t)b * HW + nb + n) * 256 + cb + cq * 4] = u;
    }
}

// ---- MFMA GEMM: D[o][n] = sum_c W[o][c] * XT[n][c], per batch b ----
template <int EPI>
__global__ __launch_bounds__(256) void gemm_mfma(
    const ushort* __restrict__ W, const ushort* __restrict__ XT, int K,
    long syb,
    const float* __restrict__ q0, const float* __restrict__ q1,
    const float* __restrict__ q2, const float* __restrict__ q3,
    const float* __restrict__ R, float* __restrict__ Yf,
    ushort* __restrict__ U0, ushort* __restrict__ U1, ushort* __restrict__ U2,
    int uoff)
{
    const int b = blockIdx.z;
    const int t = threadIdx.x;
    const int w = t >> 6, l = t & 63;
    const int ln = l & 15, lg = l >> 4;
    const int wo = (w & 1) * 64, wn = (w >> 1) * 64;
    const int ob = blockIdx.y * 128 + wo;
    const int nb = blockIdx.x * 128 + wn;

    const ushort* ap = W + (size_t)(ob + ln) * K + lg * 8;
    const ushort* bp = XT + ((size_t)b * HW + nb + ln) * K + lg * 8;

    bf16x8 a0[4], bb0[4], a1[4], bb1[4];
    #pragma unroll
    for (int i = 0; i < 4; i++) {
        a0[i]  = *(const bf16x8*)(ap + (size_t)i * 16 * K);
        bb0[i] = *(const bf16x8*)(bp + (size_t)i * 16 * K);
    }
    f32x4 acc[4][4];
    #pragma unroll
    for (int i = 0; i < 4; i++)
        #pragma unroll
        for (int j = 0; j < 4; j++) acc[i][j] = (f32x4){0.f, 0.f, 0.f, 0.f};

    for (int c0 = 32; c0 <= K; c0 += 32) {
        if (c0 < K) {
            #pragma unroll
            for (int i = 0; i < 4; i++) {
                a1[i]  = *(const bf16x8*)(ap + (size_t)i * 16 * K + c0);
                bb1[i] = *(const bf16x8*)(bp + (size_t)i * 16 * K + c0);
            }
        }
        #pragma unroll
        for (int i = 0; i < 4; i++)
            #pragma unroll
            for (int j = 0; j < 4; j++)
                acc[i][j] = __builtin_amdgcn_mfma_f32_16x16x32_bf16(a0[i], bb0[j], acc[i][j], 0, 0, 0);
        #pragma unroll
        for (int i = 0; i < 4; i++) { a0[i] = a1[i]; bb0[i] = bb1[i]; }
    }

    #pragma unroll
    for (int i = 0; i < 4; i++) {
        const int obase = ob + i * 16 + lg * 4;   // 4 consecutive o (r=0..3)
        if (EPI == E_CV1 || EPI == E_CV2) {
            float sc[4], sh[4];
            #pragma unroll
            for (int r = 0; r < 4; r++) {
                const int o = obase + r;
                const float rs = rsqrtf(q3[o] + EPSV);
                sc[r] = q0[o] * rs;
                sh[r] = q1[o] - q2[o] * sc[r];
            }
            #pragma unroll
            for (int j = 0; j < 4; j++) {
                const int n = nb + j * 16 + ln;
                ushort4 u;
                #pragma unroll
                for (int r = 0; r < 4; r++) {
                    float y = fmaf(acc[i][j][r], sc[r], sh[r]);
                    y = y / (1.f + __expf(-y));
                    Yf[(size_t)b * syb + (size_t)(obase + r) * HW + n] = y;
                    if (EPI == E_CV1) {
                        if (r == 0) u.x = b16(y); else if (r == 1) u.y = b16(y);
                        else if (r == 2) u.z = b16(y); else u.w = b16(y);
                    }
                }
                if (EPI == E_CV1)
                    *(ushort4*)&U0[((size_t)b * HW + n) * 512 + obase] = u;
            }
        } else if (EPI == E_QKV) {
            // Reference quirk: Q = batch0's full 384ch, K = batch1's, V = batch2's.
            const int gh = obase >> 5;   // (chunk*4 + head), 0..11
            const int d0 = obase & 31;
            float bias[4];
            #pragma unroll
            for (int r = 0; r < 4; r++) bias[r] = q0[obase + r];
            #pragma unroll
            for (int j = 0; j < 4; j++) {
                const int n = nb + j * 16 + ln;
                if (b == 0) {
                    ushort4 u;
                    u.x = b16((acc[i][j][0] + bias[0]) * QS_LOG2E);
                    u.y = b16((acc[i][j][1] + bias[1]) * QS_LOG2E);
                    u.z = b16((acc[i][j][2] + bias[2]) * QS_LOG2E);
                    u.w = b16((acc[i][j][3] + bias[3]) * QS_LOG2E);
                    *(ushort4*)&U0[((size_t)gh * HW + n) * 32 + d0] = u;
                } else if (b == 1) {
                    ushort4 u;
                    u.x = b16(acc[i][j][0] + bias[0]);
                    u.y = b16(acc[i][j][1] + bias[1]);
                    u.z = b16(acc[i][j][2] + bias[2]);
                    u.w = b16(acc[i][j][3] + bias[3]);
                    *(ushort4*)&U1[((size_t)gh * HW + n) * 32 + d0] = u;
                } else {
                    #pragma unroll
                    for (int r = 0; r < 4; r++)
                        U2[(size_t)(obase + r) * HW + n] = b16(acc[i][j][r] + bias[r]);
                }
            }
        } else if (EPI == E_PROJ || EPI == E_F2) {
            #pragma unroll
            for (int j = 0; j < 4; j++) {
                const int n = nb + j * 16 + ln;
                ushort4 u;
                #pragma unroll
                for (int r = 0; r < 4; r++) {
                    const int o = obase + r;
                    float y = acc[i][j][r] + q0[o]
                            + R[(size_t)b * syb + (size_t)o * HW + n];
                    Yf[(size_t)b * syb + (size_t)o * HW + n] = y;
                    if (EPI == E_F2) {
                        if (r == 0) u.x = b16(y); else if (r == 1) u.y = b16(y);
                        else if (r == 2) u.z = b16(y); else u.w = b16(y);
                    }
                }
                if (EPI == E_F2)
                    *(ushort4*)&U0[((size_t)b * HW + n) * 512 + uoff + obase] = u;
            }
        } else {  // E_F1: gelu -> FT bf16 [n][256]
            float bias[4];
            #pragma unroll
            for (int r = 0; r < 4; r++) bias[r] = q0[obase + r];
            #pragma unroll
            for (int j = 0; j < 4; j++) {
                const int n = nb + j * 16 + ln;
                ushort4 u;
                #pragma unroll
                for (int r = 0; r < 4; r++) {
                    float y = acc[i][j][r] + bias[r];
                    y = 0.5f * y * (1.f + erff(y * 0.70710678f));
                    if (r == 0) u.x = b16(y); else if (r == 1) u.y = b16(y);
                    else if (r == 2) u.z = b16(y); else u.w = b16(y);
                }
                *(ushort4*)&U0[((size_t)b * HW + n) * 256 + obase] = u;
            }
        }
    }
}

// ---- GroupNorm stats (fp32 CAT) ----
__global__ __launch_bounds__(256) void gn_partial(
    const float* __restrict__ X, long sxb, float* __restrict__ stats)
{
    const int b = blockIdx.y;
    const float* xb = X + (size_t)b * sxb + (size_t)blockIdx.x * 6144;
    float s = 0.f, sq = 0.f;
    #pragma unroll
    for (int k = 0; k < 6; k++) {
        float4 v = *(const float4*)&xb[(size_t)(k * 256 + threadIdx.x) * 4];
        s  += v.x + v.y + v.z + v.w;
        sq += v.x * v.x + v.y * v.y + v.z * v.z + v.w * v.w;
    }
    #pragma unroll
    for (int off = 32; off; off >>= 1) { s += __shfl_xor(s, off); sq += __shfl_xor(sq, off); }
    __shared__ float ps[4], pq[4];
    const int wave = threadIdx.x >> 6, lane = threadIdx.x & 63;
    if (lane == 0) { ps[wave] = s; pq[wave] = sq; }
    __syncthreads();
    if (threadIdx.x == 0) {
        stats[b * 48 + blockIdx.x]       = ps[0] + ps[1] + ps[2] + ps[3];
        stats[144 + b * 48 + blockIdx.x] = pq[0] + pq[1] + pq[2] + pq[3];
    }
}

__global__ void gn_reduce(float* __restrict__ stats)
{
    const int b = blockIdx.x, t = threadIdx.x;
    float s  = (t < 48) ? stats[b * 48 + t] : 0.f;
    float sq = (t < 48) ? stats[144 + b * 48 + t] : 0.f;
    #pragma unroll
    for (int off = 32; off; off >>= 1) { s += __shfl_xor(s, off); sq += __shfl_xor(sq, off); }
    if (t == 0) {
        const float inv = 1.f / 294912.f;
        const float mean = s * inv;
        const float var  = sq * inv - mean * mean;
        stats[288 + b] = mean;
        stats[292 + b] = rsqrtf(var + EPSV);
    }
}

// ---- GN apply -> ZT bf16 [b][n][128], LDS transpose, coalesced ----
__global__ __launch_bounds__(256) void gn_apply_t(
    const float* __restrict__ X, long sxb, ushort* __restrict__ ZT,
    const float* __restrict__ g, const float* __restrict__ bb,
    const float* __restrict__ stats)
{
    __shared__ ushort tb[64][68];
    const int b = blockIdx.z, cb = blockIdx.y * 64, nb = blockIdx.x * 64;
    const float mean = stats[288 + b];
    const float rs   = stats[292 + b];
    const int t = threadIdx.x;
    #pragma unroll
    for (int k = 0; k < 4; k++) {
        const int row = k * 16 + (t >> 4), cq = t & 15;
        const int c = cb + row;
        const float sc = rs * g[c];
        const float sh = bb[c] - mean * sc;
        float4 v = *(const float4*)&X[(size_t)b * sxb + (size_t)c * HW + nb + cq * 4];
        ushort4 u;
        u.x = b16(fmaf(v.x, sc, sh)); u.y = b16(fmaf(v.y, sc, sh));
        u.z = b16(fmaf(v.z, sc, sh)); u.w = b16(fmaf(v.w, sc, sh));
        *(ushort4*)&tb[row][cq * 4] = u;
    }
    __syncthreads();
    #pragma unroll
    for (int k = 0; k < 4; k++) {
        const int n = k * 16 + (t >> 4), cq = t & 15;
        ushort4 u;
        u.x = tb[cq * 4 + 0][n]; u.y = tb[cq * 4 + 1][n];
        u.z = tb[cq * 4 + 2][n]; u.w = tb[cq * 4 + 3][n];
        *(ushort4*)&ZT[((size_t)b * HW + nb + n) * 128 + cb + cq * 4] = u;
    }
}

// ---- MFMA flash attention, split-K=2, LDS-staged K/V shared by 4 waves ----
// grid (36, 12, 2); 256 threads = 4 waves, each 16 queries; 64-key tiles.
__global__ __launch_bounds__(256) void attn_mfma(
    const ushort* __restrict__ QT,  // [12][HW][32] bf16, pre-scaled by QS_LOG2E
    const ushort* __restrict__ KT,  // [12][HW][32] bf16
    const ushort* __restrict__ VB,  // [384][HW] bf16 (batch2 channels)
    float* __restrict__ PO0, float* __restrict__ PO1,
    float* __restrict__ MS)         // [2][12][HW][2]
{
    __shared__ __align__(16) ushort Kl[2][2048];   // 64 m-rows x 32 d (64B rows)
    __shared__ __align__(16) ushort Vl[2][2048];   // 32 d-rows x 64 m (128B rows)
    __shared__ __align__(16) ushort plds[4][16][72];
    const int gh = blockIdx.y, g = gh >> 2, h = gh & 3;
    const int half = blockIdx.z;
    const int t = threadIdx.x, w = t >> 6, l = t & 63;
    const int ln = l & 15, lg = l >> 4;
    const int n0 = (blockIdx.x * 4 + w) * 16;
    const int ms0 = half * 1152, mend = ms0 + 1152;

    const ushort* ktg = KT + (size_t)gh * HW * 32;
    const ushort* vg  = VB + ((size_t)g * 128 + h * 32) * HW;

    // staging indices (per thread)
    const int krow = t >> 2, kcq = t & 3;
    const int vrow = t >> 3, vcq = t & 7;
    const int kw = krow * 32 + ((kcq ^ (krow & 3)) << 3);
    const int vw = vrow * 64 + ((vcq ^ (vrow & 7)) << 3);
    // fragment read offsets (swizzle matches writes)
    const int krd = ln * 32 + ((lg ^ (ln & 3)) << 3);
    const int vs  = ln & 7;
    const int vrd0 = ln * 64 + ((lg ^ vs) << 3);
    const int vrd1 = ln * 64 + (((lg + 4) ^ vs) << 3);
    const int vrd2 = (16 + ln) * 64 + ((lg ^ vs) << 3);
    const int vrd3 = (16 + ln) * 64 + (((lg + 4) ^ vs) << 3);

    const bf16x8 qf = *(const bf16x8*)(QT + ((size_t)gh * HW + n0 + ln) * 32 + lg * 8);

    f32x4 o0 = {0.f, 0.f, 0.f, 0.f}, o1 = {0.f, 0.f, 0.f, 0.f};
    float M = -3.0e38f, S = 0.f;

    // prologue: stage first tile
    {
        bf16x8 kr = *(const bf16x8*)(ktg + (size_t)(ms0 + krow) * 32 + kcq * 8);
        bf16x8 vr = *(const bf16x8*)(vg + (size_t)vrow * HW + ms0 + vcq * 8);
        *(bf16x8*)&Kl[0][kw] = kr;
        *(bf16x8*)&Vl[0][vw] = vr;
    }
    int cur = 0;

    for (int m0 = ms0; m0 < mend; m0 += 64) {
        __syncthreads();                    // buf[cur] ready
        const bool more = (m0 + 64 < mend);
        bf16x8 kr, vr;
        if (more) {
            kr = *(const bf16x8*)(ktg + (size_t)(m0 + 64 + krow) * 32 + kcq * 8);
            vr = *(const bf16x8*)(vg + (size_t)vrow * HW + m0 + 64 + vcq * 8);
        }

        f32x4 st[4];
        const f32x4 zero = {0.f, 0.f, 0.f, 0.f};
        #pragma unroll
        for (int mc = 0; mc < 4; mc++) {
            const bf16x8 kf = *(const bf16x8*)&Kl[cur][mc * 512 + krd];
            st[mc] = __builtin_amdgcn_mfma_f32_16x16x32_bf16(kf, qf, zero, 0, 0, 0);
        }

        float mx = st[0][0];
        #pragma unroll
        for (int mc = 0; mc < 4; mc++)
            #pragma unroll
            for (int r = 0; r < 4; r++) mx = fmaxf(mx, st[mc][r]);
        mx = fmaxf(mx, __shfl_xor(mx, 16));
        mx = fmaxf(mx, __shfl_xor(mx, 32));
        if (!__all(mx <= M + 8.f)) {        // defer-max: skip rescale when bounded
            const float Mn = fmaxf(M, mx);
            const float corr = exp2f(M - Mn);
            S *= corr;
            #pragma unroll
            for (int r = 0; r < 4; r++) { o0[r] *= corr; o1[r] *= corr; }
            M = Mn;
        }
        float ps = 0.f;
        ushort4 pw[4];
        #pragma unroll
        for (int mc = 0; mc < 4; mc++) {
            float p0v = exp2f(st[mc][0] - M), p1v = exp2f(st[mc][1] - M);
            float p2v = exp2f(st[mc][2] - M), p3v = exp2f(st[mc][3] - M);
            ps += (p0v + p1v) + (p2v + p3v);
            pw[mc].x = b16(p0v); pw[mc].y = b16(p1v);
            pw[mc].z = b16(p2v); pw[mc].w = b16(p3v);
        }
        ps += __shfl_xor(ps, 16);
        ps += __shfl_xor(ps, 32);
        S += ps;

        #pragma unroll
        for (int mc = 0; mc < 4; mc++)
            *(ushort4*)&plds[w][ln][mc * 16 + lg * 4] = pw[mc];
        bf16x8 pf0 = *(const bf16x8*)&plds[w][ln][lg * 8];
        bf16x8 pf1 = *(const bf16x8*)&plds[w][ln][32 + lg * 8];

        const bf16x8 vf0 = *(const bf16x8*)&Vl[cur][vrd0];
        const bf16x8 vf1 = *(const bf16x8*)&Vl[cur][vrd1];
        const bf16x8 vf2 = *(const bf16x8*)&Vl[cur][vrd2];
        const bf16x8 vf3 = *(const bf16x8*)&Vl[cur][vrd3];
        o0 = __builtin_amdgcn_mfma_f32_16x16x32_bf16(vf0, pf0, o0, 0, 0, 0);
        o0 = __builtin_amdgcn_mfma_f32_16x16x32_bf16(vf1, pf1, o0, 0, 0, 0);
        o1 = __builtin_amdgcn_mfma_f32_16x16x32_bf16(vf2, pf0, o1, 0, 0, 0);
        o1 = __builtin_amdgcn_mfma_f32_16x16x32_bf16(vf3, pf1, o1, 0, 0, 0);

        if (more) {
            *(bf16x8*)&Kl[cur ^ 1][kw] = kr;
            *(bf16x8*)&Vl[cur ^ 1][vw] = vr;
        }
        cur ^= 1;
    }

    float* po = half ? PO1 : PO0;
    #pragma unroll
    for (int r = 0; r < 4; r++) {
        const int d = lg * 4 + r;
        po[((size_t)gh * 32 + d) * HW + n0 + ln]      = o0[r];
        po[((size_t)gh * 32 + d + 16) * HW + n0 + ln] = o1[r];
    }
    if (lg == 0) {
        float* ms = MS + (((size_t)half * 12 + gh) * HW + n0 + ln) * 2;
        ms[0] = M; ms[1] = S;
    }
}

// ---- merge split-K partials -> AOT bf16 [g][n][128] (channel = d*4+h) ----
// grid (36, 3); coalesced reads, LDS bounce, contiguous 16B stores.
__global__ __launch_bounds__(256) void attn_merge(
    const float* __restrict__ PO0, const float* __restrict__ PO1,
    const float* __restrict__ MS, ushort* __restrict__ AOT)
{
    __shared__ float fw0[4][64], fw1[4][64];
    __shared__ unsigned long long obuf[64][33];
    const int g = blockIdx.y, nb = blockIdx.x * 64;
    const int t = threadIdx.x;
    {
        const int h = t >> 6, nl = t & 63, gh = g * 4 + h, n = nb + nl;
        const float M0 = MS[((size_t)gh * HW + n) * 2 + 0];
        const float S0 = MS[((size_t)gh * HW + n) * 2 + 1];
        const float M1 = MS[(((size_t)12 + gh) * HW + n) * 2 + 0];
        const float S1 = MS[(((size_t)12 + gh) * HW + n) * 2 + 1];
        const float Mx = fmaxf(M0, M1);
        float w0 = exp2f(M0 - Mx), w1 = exp2f(M1 - Mx);
        const float inv = 1.f / (S0 * w0 + S1 * w1);
        fw0[h][nl] = w0 * inv;
        fw1[h][nl] = w1 * inv;
    }
    __syncthreads();
    const int nl = t & 63, dd = t >> 6;
    #pragma unroll
    for (int p = 0; p < 8; p++) {
        const int d = p * 4 + dd;
        ushort uu[4];
        #pragma unroll
        for (int h = 0; h < 4; h++) {
            const int gh = g * 4 + h;
            const size_t idx = ((size_t)gh * 32 + d) * HW + nb + nl;
            const float v = PO0[idx] * fw0[h][nl] + PO1[idx] * fw1[h][nl];
            uu[h] = b16(v);
        }
        obuf[nl][d] = (unsigned long long)uu[0] | ((unsigned long long)uu[1] << 16)
                    | ((unsigned long long)uu[2] << 32) | ((unsigned long long)uu[3] << 48);
    }
    __syncthreads();
    #pragma unroll
    for (int w = 0; w < 4; w++) {
        const int flat = w * 256 + t;
        const int n = flat >> 4, seg = flat & 15;
        u64x2 val;
        val[0] = obuf[n][seg * 2];
        val[1] = obuf[n][seg * 2 + 1];
        *(u64x2*)&AOT[((size_t)g * HW + nb + n) * 128 + seg * 8] = val;
    }
}

extern "C" void kernel_launch(void* const* d_in, const int* in_sizes, int n_in,
                              void* d_out, int out_size, void* d_ws, size_t ws_size,
                              hipStream_t stream)
{
    (void)in_sizes; (void)n_in; (void)out_size; (void)ws_size;
    const float* x      = (const float*)d_in[0];
    const float* cv1_w  = (const float*)d_in[1];
    const float* cv1_g  = (const float*)d_in[2];
    const float* cv1_b  = (const float*)d_in[3];
    const float* cv1_m  = (const float*)d_in[4];
    const float* cv1_v  = (const float*)d_in[5];
    const float* n1_g   = (const float*)d_in[6];
    const float* n1_b   = (const float*)d_in[7];
    const float* qkv_w  = (const float*)d_in[8];
    const float* qkv_b  = (const float*)d_in[9];
    const float* proj_w = (const float*)d_in[10];
    const float* proj_b = (const float*)d_in[11];
    const float* n2_g   = (const float*)d_in[12];
    const float* n2_b   = (const float*)d_in[13];
    const float* f1_w   = (const float*)d_in[14];
    const float* f1_b   = (const float*)d_in[15];
    const float* f2_w   = (const float*)d_in[16];
    const float* f2_b   = (const float*)d_in[17];
    const float* cv2_w  = (const float*)d_in[18];
    const float* cv2_g  = (const float*)d_in[19];
    const float* cv2_b  = (const float*)d_in[20];
    const float* cv2_m  = (const float*)d_in[21];
    const float* cv2_v  = (const float*)d_in[22];
    float* out = (float*)d_out;

    float* ws = (float*)d_ws;
    float*  CAT  = ws;                               // 3x512xHW fp32
    ushort* CATT = (ushort*)(ws + 3538944);          // [3][HW][512] bf16
    ushort* ZT   = (ushort*)(ws + 5308416);          // [3][HW][128] bf16
    ushort* QT   = (ushort*)(ws + 5750784);          // [12][HW][32] bf16
    ushort* KTb  = (ushort*)(ws + 6193152);          // [12][HW][32] bf16
    ushort* VB   = (ushort*)(ws + 6635520);          // [384][HW] bf16
    ushort* FT   = QT;                               // [3][HW][256] bf16 (alias, disjoint)
    float*  MS   = ws + 7077888;                     // [2][12][HW][2]
    ushort* AOT  = (ushort*)(ws + 7188480);          // [3][HW][128] bf16
    ushort* WB   = (ushort*)(ws + 7630848);          // 458752 bf16 weights
    float*  STAT = ws + 7860224;                     // 512
    // d_out doubles as scratch (fully rewritten each call):
    ushort* XTX  = (ushort*)d_out;                   // [3][HW][256] bf16 (dead after cv1)
    float*  PO0  = (float*)d_out;                    // [12][32][HW] fp32 (attention)
    float*  PO1  = PO0 + 884736;

    const long sCAT = 512L * HW, sOUT = 256L * HW;
    dim3 blk(256);

    cvt_w<<<dim3(448), blk, 0, stream>>>(cv1_w, qkv_w, proj_w, f1_w, f2_w, cv2_w, WB);
    txp_x<<<dim3(36, 4, 3), blk, 0, stream>>>(x, XTX);

    // cv1: 256ch <- 256ch, BN+SiLU -> CAT rows 0..255 (fp32) + CATT cols 0..255
    gemm_mfma<E_CV1><<<dim3(18, 2, 3), blk, 0, stream>>>(
        WB + 0, XTX, 256, sCAT, cv1_g, cv1_b, cv1_m, cv1_v,
        nullptr, CAT, CATT, nullptr, nullptr, 0);

    for (int i = 0; i < 2; i++) {
        const long prev = (i == 0) ? 128L : 256L;
        const long next = 256L + 128L * i;

        gn_partial<<<dim3(48, 3), blk, 0, stream>>>(CAT + prev * HW, sCAT, STAT);
        gn_reduce<<<dim3(3), dim3(64), 0, stream>>>(STAT);
        gn_apply_t<<<dim3(36, 2, 3), blk, 0, stream>>>(CAT + prev * HW, sCAT, ZT,
                                                       n1_g + i * 128, n1_b + i * 128, STAT);
        gemm_mfma<E_QKV><<<dim3(18, 3, 3), blk, 0, stream>>>(
            WB + 65536 + (size_t)i * 49152, ZT, 128, 0, qkv_b + i * 384,
            nullptr, nullptr, nullptr, nullptr, nullptr, QT, KTb, VB, 0);
        attn_mfma<<<dim3(36, 12, 2), blk, 0, stream>>>(QT, KTb, VB, PO0, PO1, MS);
        attn_merge<<<dim3(36, 3), blk, 0, stream>>>(PO0, PO1, MS, AOT);
        gemm_mfma<E_PROJ><<<dim3(18, 1, 3), blk, 0, stream>>>(
            WB + 163840 + (size_t)i * 16384, AOT, 128, sCAT, proj_b + i * 128,
            nullptr, nullptr, nullptr, CAT + prev * HW, CAT + next * HW,
            nullptr, nullptr, nullptr, 0);

        gn_partial<<<dim3(48, 3), blk, 0, stream>>>(CAT + next * HW, sCAT, STAT);
        gn_reduce<<<dim3(3), dim3(64), 0, stream>>>(STAT);
        gn_apply_t<<<dim3(36, 2, 3), blk, 0, stream>>>(CAT + next * HW, sCAT, ZT,
                                                       n2_g + i * 128, n2_b + i * 128, STAT);
        gemm_mfma<E_F1><<<dim3(18, 2, 3), blk, 0, stream>>>(
            WB + 196608 + (size_t)i * 32768, ZT, 128, 0, f1_b + i * 256,
            nullptr, nullptr, nullptr, nullptr, nullptr, FT, nullptr, nullptr, 0);
        gemm_mfma<E_F2><<<dim3(18, 1, 3), blk, 0, stream>>>(
            WB + 262144 + (size_t)i * 32768, FT, 256, sCAT, f2_b + i * 128,
            nullptr, nullptr, nullptr, CAT + next * HW, CAT + next * HW,
            CATT, nullptr, nullptr, (int)next);
    }

    // cv2: 256ch <- 512ch concat, BN+SiLU -> out
    gemm_mfma<E_CV2><<<dim3(18, 2, 3), blk, 0, stream>>>(
        WB + 327680, CATT, 512, sOUT, cv2_g, cv2_b, cv2_m, cv2_v,
        nullptr, out, nullptr, nullptr, nullptr, 0);
}

// Round 6
// 245.635 us; speedup vs baseline: 1.3317x; 1.0015x over previous
//
#include <hip/hip_runtime.h>
#include <hip/hip_bf16.h>
#include <math.h>

#define HW 2304
#define EPSV 1e-5f
// ATT_SCALE * log2(e): softmax runs in exp2 domain
#define QS_LOG2E (0.17677669529663687f * 1.44269504088896340f)

enum { E_CV1 = 0, E_QKV = 1, E_RES = 2, E_F1 = 3, E_CV2 = 4 };

typedef __attribute__((ext_vector_type(8))) short bf16x8;
typedef __attribute__((ext_vector_type(4))) float f32x4;
typedef __attribute__((ext_vector_type(2))) unsigned long long u64x2;

static __device__ __forceinline__ ushort b16(float f) {
    union { __hip_bfloat16 h; ushort u; } cv;
    cv.h = __float2bfloat16(f);
    return cv.u;
}
static __device__ __forceinline__ float bf(ushort u) {
    union { unsigned u; float f; } c; c.u = (unsigned)u << 16; return c.f;
}

// ---- non-folded weights fp32 -> bf16: cv1|proj|f2|cv2 ----
__global__ __launch_bounds__(256) void cvt_w(
    const float* __restrict__ w0, const float* __restrict__ w1,
    const float* __restrict__ w2, const float* __restrict__ w3,
    ushort* __restrict__ WB)
{
    const int idx = (blockIdx.x * 256 + threadIdx.x) * 4;  // < 294912
    const float* src;
    int off;
    if      (idx < 65536)  { src = w0; off = 0; }
    else if (idx < 98304)  { src = w1; off = 65536; }
    else if (idx < 163840) { src = w2; off = 98304; }
    else                   { src = w3; off = 163840; }
    float4 v = *(const float4*)&src[idx - off];
    ushort4 u;
    u.x = b16(v.x); u.y = b16(v.y); u.z = b16(v.z); u.w = b16(v.w);
    *(ushort4*)&WB[idx] = u;
}

// ---- fold GN affine into qkv/f1 weights + correction vectors ----
// FW: [i][384][128] qkv then @98304 [i][256][128] f1 (bf16)
// CV per i (1280 f): SWq[384] | WBq[384] | SWf[256] | WBf[256]
__global__ __launch_bounds__(256) void fold_w(
    const float* __restrict__ qw, const float* __restrict__ g1, const float* __restrict__ b1,
    const float* __restrict__ fw1, const float* __restrict__ g2, const float* __restrict__ b2,
    ushort* __restrict__ FW, float* __restrict__ CV)
{
    const int idx = blockIdx.x * 256 + threadIdx.x;  // < 1280
    if (idx >= 1280) return;
    const int i = idx / 640, r = idx % 640;
    float sw = 0.f, wb = 0.f;
    if (r < 384) {
        const float* wrow = qw + ((size_t)i * 384 + r) * 128;
        const float* gg = g1 + i * 128;
        const float* bb = b1 + i * 128;
        ushort* dst = FW + (size_t)i * 49152 + r * 128;
        for (int c = 0; c < 128; c++) {
            const float w = wrow[c], wp = w * gg[c];
            dst[c] = b16(wp); sw += wp; wb += w * bb[c];
        }
        CV[i * 1280 + r] = sw;
        CV[i * 1280 + 384 + r] = wb;
    } else {
        const int o = r - 384;
        const float* wrow = fw1 + ((size_t)i * 256 + o) * 128;
        const float* gg = g2 + i * 128;
        const float* bb = b2 + i * 128;
        ushort* dst = FW + 98304 + (size_t)i * 32768 + o * 128;
        for (int c = 0; c < 128; c++) {
            const float w = wrow[c], wp = w * gg[c];
            dst[c] = b16(wp); sw += wp; wb += w * bb[c];
        }
        CV[i * 1280 + 768 + o] = sw;
        CV[i * 1280 + 1024 + o] = wb;
    }
}

// ---- x fp32 [3][256][HW] -> bf16 [3][HW][256], LDS transpose ----
__global__ __launch_bounds__(256) void txp_x(
    const float* __restrict__ X, ushort* __restrict__ XT)
{
    __shared__ ushort tb[64][68];
    const int b = blockIdx.z, cb = blockIdx.y * 64, nb = blockIdx.x * 64;
    const int t = threadIdx.x;
    #pragma unroll
    for (int k = 0; k < 4; k++) {
        const int row = k * 16 + (t >> 4), cq = t & 15;
        float4 v = *(const float4*)&X[(size_t)(b * 256 + cb + row) * HW + nb + cq * 4];
        ushort4 u; u.x = b16(v.x); u.y = b16(v.y); u.z = b16(v.z); u.w = b16(v.w);
        *(ushort4*)&tb[row][cq * 4] = u;
    }
    __syncthreads();
    #pragma unroll
    for (int k = 0; k < 4; k++) {
        const int n = k * 16 + (t >> 4), cq = t & 15;
        ushort4 u;
        u.x = tb[cq * 4 + 0][n]; u.y = tb[cq * 4 + 1][n];
        u.z = tb[cq * 4 + 2][n]; u.w = tb[cq * 4 + 3][n];
        *(ushort4*)&XT[((size_t)b * HW + nb + n) * 256 + cb + cq * 4] = u;
    }
}

// ---- MFMA GEMM: D[o][n] = sum_c W[o][c] * X[n][xoff+c], per batch b ----
template <int EPI>
__global__ __launch_bounds__(256) void gemm_mfma(
    const ushort* __restrict__ W, const ushort* __restrict__ X,
    int K, int xld, int xoff,
    const float* __restrict__ q0, const float* __restrict__ q1,
    const float* __restrict__ q2, const float* __restrict__ q3,
    const float* __restrict__ stats, const float* __restrict__ cvec,
    ushort* __restrict__ CT, int rcol, int ycol,
    float* __restrict__ Yf,
    ushort* __restrict__ U0, ushort* __restrict__ U1, ushort* __restrict__ U2)
{
    const int b = blockIdx.z;
    const int t = threadIdx.x;
    const int w = t >> 6, l = t & 63;
    const int ln = l & 15, lg = l >> 4;
    const int wo = (w & 1) * 64, wn = (w >> 1) * 64;
    const int ob = blockIdx.y * 128 + wo;
    const int nb = blockIdx.x * 128 + wn;

    const ushort* ap = W + (size_t)(ob + ln) * K + lg * 8;
    const ushort* bp = X + ((size_t)b * HW + nb + ln) * xld + xoff + lg * 8;

    bf16x8 a0[4], bb0[4], a1[4], bb1[4];
    #pragma unroll
    for (int i = 0; i < 4; i++) {
        a0[i]  = *(const bf16x8*)(ap + (size_t)i * 16 * K);
        bb0[i] = *(const bf16x8*)(bp + (size_t)i * 16 * xld);
    }
    f32x4 acc[4][4];
    #pragma unroll
    for (int i = 0; i < 4; i++)
        #pragma unroll
        for (int j = 0; j < 4; j++) acc[i][j] = (f32x4){0.f, 0.f, 0.f, 0.f};

    for (int c0 = 32; c0 <= K; c0 += 32) {
        if (c0 < K) {
            #pragma unroll
            for (int i = 0; i < 4; i++) {
                a1[i]  = *(const bf16x8*)(ap + (size_t)i * 16 * K + c0);
                bb1[i] = *(const bf16x8*)(bp + (size_t)i * 16 * xld + c0);
            }
        }
        #pragma unroll
        for (int i = 0; i < 4; i++)
            #pragma unroll
            for (int j = 0; j < 4; j++)
                acc[i][j] = __builtin_amdgcn_mfma_f32_16x16x32_bf16(a0[i], bb0[j], acc[i][j], 0, 0, 0);
        #pragma unroll
        for (int i = 0; i < 4; i++) { a0[i] = a1[i]; bb0[i] = bb1[i]; }
    }

    const float mu = (EPI == E_QKV || EPI == E_F1) ? stats[288 + b] : 0.f;
    const float rs = (EPI == E_QKV || EPI == E_F1) ? stats[292 + b] : 0.f;

    #pragma unroll
    for (int i = 0; i < 4; i++) {
        const int obase = ob + i * 16 + lg * 4;   // 4 consecutive o (r=0..3)
        if (EPI == E_CV1 || EPI == E_CV2) {
            float sc[4], sh[4];
            #pragma unroll
            for (int r = 0; r < 4; r++) {
                const int o = obase + r;
                const float irs = rsqrtf(q3[o] + EPSV);
                sc[r] = q0[o] * irs;
                sh[r] = q1[o] - q2[o] * sc[r];
            }
            #pragma unroll
            for (int j = 0; j < 4; j++) {
                const int n = nb + j * 16 + ln;
                ushort4 u;
                #pragma unroll
                for (int r = 0; r < 4; r++) {
                    float y = fmaf(acc[i][j][r], sc[r], sh[r]);
                    y = y / (1.f + __expf(-y));
                    if (EPI == E_CV2) {
                        Yf[(size_t)(b * 256 + obase + r) * HW + n] = y;
                    } else {
                        if (r == 0) u.x = b16(y); else if (r == 1) u.y = b16(y);
                        else if (r == 2) u.z = b16(y); else u.w = b16(y);
                    }
                }
                if (EPI == E_CV1)
                    *(ushort4*)&CT[((size_t)b * HW + n) * 512 + ycol + obase] = u;
            }
        } else if (EPI == E_QKV) {
            // Q = batch0's 384ch, K = batch1's, V = batch2's (reference quirk).
            const int gh = obase >> 5;   // chunk*4 + head
            const int d0 = obase & 31;
            float C[4];
            #pragma unroll
            for (int r = 0; r < 4; r++) {
                const int o = obase + r;
                C[r] = q0[o] + cvec[384 + o] - rs * mu * cvec[o];
            }
            #pragma unroll
            for (int j = 0; j < 4; j++) {
                const int n = nb + j * 16 + ln;
                float y0 = fmaf(rs, acc[i][j][0], C[0]);
                float y1 = fmaf(rs, acc[i][j][1], C[1]);
                float y2 = fmaf(rs, acc[i][j][2], C[2]);
                float y3 = fmaf(rs, acc[i][j][3], C[3]);
                if (b == 0) {
                    ushort4 u;
                    u.x = b16(y0 * QS_LOG2E); u.y = b16(y1 * QS_LOG2E);
                    u.z = b16(y2 * QS_LOG2E); u.w = b16(y3 * QS_LOG2E);
                    *(ushort4*)&U0[((size_t)gh * HW + n) * 32 + d0] = u;
                } else if (b == 1) {
                    ushort4 u;
                    u.x = b16(y0); u.y = b16(y1); u.z = b16(y2); u.w = b16(y3);
                    *(ushort4*)&U1[((size_t)gh * HW + n) * 32 + d0] = u;
                } else {
                    U2[(size_t)(obase + 0) * HW + n] = b16(y0);
                    U2[(size_t)(obase + 1) * HW + n] = b16(y1);
                    U2[(size_t)(obase + 2) * HW + n] = b16(y2);
                    U2[(size_t)(obase + 3) * HW + n] = b16(y3);
                }
            }
        } else if (EPI == E_RES) {
            #pragma unroll
            for (int j = 0; j < 4; j++) {
                const int n = nb + j * 16 + ln;
                const size_t base = ((size_t)b * HW + n) * 512;
                ushort4 rv = *(const ushort4*)&CT[base + rcol + obase];
                ushort4 u;
                u.x = b16(acc[i][j][0] + q0[obase + 0] + bf(rv.x));
                u.y = b16(acc[i][j][1] + q0[obase + 1] + bf(rv.y));
                u.z = b16(acc[i][j][2] + q0[obase + 2] + bf(rv.z));
                u.w = b16(acc[i][j][3] + q0[obase + 3] + bf(rv.w));
                *(ushort4*)&CT[base + ycol + obase] = u;
            }
        } else {  // E_F1: gelu(rs*acc + C) -> FT bf16 [b][n][256]
            float C[4];
            #pragma unroll
            for (int r = 0; r < 4; r++) {
                const int o = obase + r;
                C[r] = q0[o] + cvec[256 + o] - rs * mu * cvec[o];
            }
            #pragma unroll
            for (int j = 0; j < 4; j++) {
                const int n = nb + j * 16 + ln;
                ushort4 u;
                #pragma unroll
                for (int r = 0; r < 4; r++) {
                    float y = fmaf(rs, acc[i][j][r], C[r]);
                    y = 0.5f * y * (1.f + erff(y * 0.70710678f));
                    if (r == 0) u.x = b16(y); else if (r == 1) u.y = b16(y);
                    else if (r == 2) u.z = b16(y); else u.w = b16(y);
                }
                *(ushort4*)&U0[((size_t)b * HW + n) * 256 + obase] = u;
            }
        }
    }
}

// ---- GroupNorm partial stats from bf16 CATT slice [b][n][col..col+128) ----
__global__ __launch_bounds__(256) void gn_partial(
    const ushort* __restrict__ CT, int col, float* __restrict__ stats)
{
    const int b = blockIdx.y;
    const int t = threadIdx.x;
    const int rr = t >> 4, cq = t & 15;
    const ushort* base = CT + (size_t)b * HW * 512 + col + cq * 8;
    float s = 0.f, sq = 0.f;
    #pragma unroll
    for (int k = 0; k < 3; k++) {
        const int row = blockIdx.x * 48 + k * 16 + rr;
        bf16x8 v = *(const bf16x8*)(base + (size_t)row * 512);
        #pragma unroll
        for (int e = 0; e < 8; e++) {
            const float f = bf((ushort)v[e]);
            s += f; sq += f * f;
        }
    }
    #pragma unroll
    for (int off = 32; off; off >>= 1) { s += __shfl_xor(s, off); sq += __shfl_xor(sq, off); }
    __shared__ float ps[4], pq[4];
    const int wave = t >> 6, lane = t & 63;
    if (lane == 0) { ps[wave] = s; pq[wave] = sq; }
    __syncthreads();
    if (t == 0) {
        stats[b * 48 + blockIdx.x]       = ps[0] + ps[1] + ps[2] + ps[3];
        stats[144 + b * 48 + blockIdx.x] = pq[0] + pq[1] + pq[2] + pq[3];
    }
}

__global__ void gn_reduce(float* __restrict__ stats)
{
    const int b = blockIdx.x, t = threadIdx.x;
    float s  = (t < 48) ? stats[b * 48 + t] : 0.f;
    float sq = (t < 48) ? stats[144 + b * 48 + t] : 0.f;
    #pragma unroll
    for (int off = 32; off; off >>= 1) { s += __shfl_xor(s, off); sq += __shfl_xor(sq, off); }
    if (t == 0) {
        const float inv = 1.f / 294912.f;
        const float mean = s * inv;
        const float var  = sq * inv - mean * mean;
        stats[288 + b] = mean;
        stats[292 + b] = rsqrtf(var + EPSV);
    }
}

// ---- MFMA flash attention, split-K=4, LDS-staged K/V shared by 4 waves ----
// grid (36, 12, 4); 256 threads = 4 waves, each 16 queries; 64-key tiles.
__global__ __launch_bounds__(256) void attn_mfma(
    const ushort* __restrict__ QT,  // [12][HW][32] bf16, pre-scaled by QS_LOG2E
    const ushort* __restrict__ KT,  // [12][HW][32] bf16
    const ushort* __restrict__ VB,  // [384][HW] bf16
    float* __restrict__ PO0, float* __restrict__ PO1,
    float* __restrict__ PO2, float* __restrict__ PO3,
    float* __restrict__ MS)         // [4][12][HW][2]
{
    __shared__ __align__(16) ushort Kl[2][2048];
    __shared__ __align__(16) ushort Vl[2][2048];
    __shared__ __align__(16) ushort plds[4][16][72];
    const int gh = blockIdx.y, g = gh >> 2, h = gh & 3;
    const int half = blockIdx.z;
    const int t = threadIdx.x, w = t >> 6, l = t & 63;
    const int ln = l & 15, lg = l >> 4;
    const int n0 = (blockIdx.x * 4 + w) * 16;
    const int ms0 = half * 576, mend = ms0 + 576;

    const ushort* ktg = KT + (size_t)gh * HW * 32;
    const ushort* vg  = VB + ((size_t)g * 128 + h * 32) * HW;

    const int krow = t >> 2, kcq = t & 3;
    const int vrow = t >> 3, vcq = t & 7;
    const int kw = krow * 32 + ((kcq ^ (krow & 3)) << 3);
    const int vw = vrow * 64 + ((vcq ^ (vrow & 7)) << 3);
    const int krd = ln * 32 + ((lg ^ (ln & 3)) << 3);
    const int vs  = ln & 7;
    const int vrd0 = ln * 64 + ((lg ^ vs) << 3);
    const int vrd1 = ln * 64 + (((lg + 4) ^ vs) << 3);
    const int vrd2 = (16 + ln) * 64 + ((lg ^ vs) << 3);
    const int vrd3 = (16 + ln) * 64 + (((lg + 4) ^ vs) << 3);

    const bf16x8 qf = *(const bf16x8*)(QT + ((size_t)gh * HW + n0 + ln) * 32 + lg * 8);

    f32x4 o0 = {0.f, 0.f, 0.f, 0.f}, o1 = {0.f, 0.f, 0.f, 0.f};
    float M = -3.0e38f, S = 0.f;

    {
        bf16x8 kr = *(const bf16x8*)(ktg + (size_t)(ms0 + krow) * 32 + kcq * 8);
        bf16x8 vr = *(const bf16x8*)(vg + (size_t)vrow * HW + ms0 + vcq * 8);
        *(bf16x8*)&Kl[0][kw] = kr;
        *(bf16x8*)&Vl[0][vw] = vr;
    }
    int cur = 0;

    for (int m0 = ms0; m0 < mend; m0 += 64) {
        __syncthreads();
        const bool more = (m0 + 64 < mend);
        bf16x8 kr, vr;
        if (more) {
            kr = *(const bf16x8*)(ktg + (size_t)(m0 + 64 + krow) * 32 + kcq * 8);
            vr = *(const bf16x8*)(vg + (size_t)vrow * HW + m0 + 64 + vcq * 8);
        }

        f32x4 st[4];
        const f32x4 zero = {0.f, 0.f, 0.f, 0.f};
        #pragma unroll
        for (int mc = 0; mc < 4; mc++) {
            const bf16x8 kf = *(const bf16x8*)&Kl[cur][mc * 512 + krd];
            st[mc] = __builtin_amdgcn_mfma_f32_16x16x32_bf16(kf, qf, zero, 0, 0, 0);
        }

        float mx = st[0][0];
        #pragma unroll
        for (int mc = 0; mc < 4; mc++)
            #pragma unroll
            for (int r = 0; r < 4; r++) mx = fmaxf(mx, st[mc][r]);
        mx = fmaxf(mx, __shfl_xor(mx, 16));
        mx = fmaxf(mx, __shfl_xor(mx, 32));
        if (!__all(mx <= M + 8.f)) {
            const float Mn = fmaxf(M, mx);
            const float corr = exp2f(M - Mn);
            S *= corr;
            #pragma unroll
            for (int r = 0; r < 4; r++) { o0[r] *= corr; o1[r] *= corr; }
            M = Mn;
        }
        float ps = 0.f;
        ushort4 pw[4];
        #pragma unroll
        for (int mc = 0; mc < 4; mc++) {
            float p0v = exp2f(st[mc][0] - M), p1v = exp2f(st[mc][1] - M);
            float p2v = exp2f(st[mc][2] - M), p3v = exp2f(st[mc][3] - M);
            ps += (p0v + p1v) + (p2v + p3v);
            pw[mc].x = b16(p0v); pw[mc].y = b16(p1v);
            pw[mc].z = b16(p2v); pw[mc].w = b16(p3v);
        }
        ps += __shfl_xor(ps, 16);
        ps += __shfl_xor(ps, 32);
        S += ps;

        #pragma unroll
        for (int mc = 0; mc < 4; mc++)
            *(ushort4*)&plds[w][ln][mc * 16 + lg * 4] = pw[mc];
        bf16x8 pf0 = *(const bf16x8*)&plds[w][ln][lg * 8];
        bf16x8 pf1 = *(const bf16x8*)&plds[w][ln][32 + lg * 8];

        const bf16x8 vf0 = *(const bf16x8*)&Vl[cur][vrd0];
        const bf16x8 vf1 = *(const bf16x8*)&Vl[cur][vrd1];
        const bf16x8 vf2 = *(const bf16x8*)&Vl[cur][vrd2];
        const bf16x8 vf3 = *(const bf16x8*)&Vl[cur][vrd3];
        o0 = __builtin_amdgcn_mfma_f32_16x16x32_bf16(vf0, pf0, o0, 0, 0, 0);
        o0 = __builtin_amdgcn_mfma_f32_16x16x32_bf16(vf1, pf1, o0, 0, 0, 0);
        o1 = __builtin_amdgcn_mfma_f32_16x16x32_bf16(vf2, pf0, o1, 0, 0, 0);
        o1 = __builtin_amdgcn_mfma_f32_16x16x32_bf16(vf3, pf1, o1, 0, 0, 0);

        if (more) {
            *(bf16x8*)&Kl[cur ^ 1][kw] = kr;
            *(bf16x8*)&Vl[cur ^ 1][vw] = vr;
        }
        cur ^= 1;
    }

    float* po = (half == 0) ? PO0 : (half == 1) ? PO1 : (half == 2) ? PO2 : PO3;
    #pragma unroll
    for (int r = 0; r < 4; r++) {
        const int d = lg * 4 + r;
        po[((size_t)gh * 32 + d) * HW + n0 + ln]      = o0[r];
        po[((size_t)gh * 32 + d + 16) * HW + n0 + ln] = o1[r];
    }
    if (lg == 0) {
        float* ms = MS + (((size_t)half * 12 + gh) * HW + n0 + ln) * 2;
        ms[0] = M; ms[1] = S;
    }
}

// ---- merge 4 split-K partials -> AOT bf16 [g][n][128] (channel = d*4+h) ----
__global__ __launch_bounds__(256) void attn_merge(
    const float* __restrict__ PO0, const float* __restrict__ PO1,
    const float* __restrict__ PO2, const float* __restrict__ PO3,
    const float* __restrict__ MS, ushort* __restrict__ AOT)
{
    __shared__ float fw[4][4][64];   // [h][half][nl]
    __shared__ unsigned long long obuf[64][33];
    const int g = blockIdx.y, nb = blockIdx.x * 64;
    const int t = threadIdx.x;
    {
        const int h = t >> 6, nl = t & 63, gh = g * 4 + h, n = nb + nl;
        float Mk[4], Sk[4];
        #pragma unroll
        for (int k = 0; k < 4; k++) {
            Mk[k] = MS[(((size_t)k * 12 + gh) * HW + n) * 2 + 0];
            Sk[k] = MS[(((size_t)k * 12 + gh) * HW + n) * 2 + 1];
        }
        const float Mx = fmaxf(fmaxf(Mk[0], Mk[1]), fmaxf(Mk[2], Mk[3]));
        float wk[4], den = 0.f;
        #pragma unroll
        for (int k = 0; k < 4; k++) { wk[k] = exp2f(Mk[k] - Mx); den += Sk[k] * wk[k]; }
        const float inv = 1.f / den;
        #pragma unroll
        for (int k = 0; k < 4; k++) fw[h][k][nl] = wk[k] * inv;
    }
    __syncthreads();
    const int nl = t & 63, dd = t >> 6;
    #pragma unroll
    for (int p = 0; p < 8; p++) {
        const int d = p * 4 + dd;
        ushort uu[4];
        #pragma unroll
        for (int h = 0; h < 4; h++) {
            const int gh = g * 4 + h;
            const size_t idx = ((size_t)gh * 32 + d) * HW + nb + nl;
            const float v = PO0[idx] * fw[h][0][nl] + PO1[idx] * fw[h][1][nl]
                          + PO2[idx] * fw[h][2][nl] + PO3[idx] * fw[h][3][nl];
            uu[h] = b16(v);
        }
        obuf[nl][d] = (unsigned long long)uu[0] | ((unsigned long long)uu[1] << 16)
                    | ((unsigned long long)uu[2] << 32) | ((unsigned long long)uu[3] << 48);
    }
    __syncthreads();
    #pragma unroll
    for (int w = 0; w < 4; w++) {
        const int flat = w * 256 + t;
        const int n = flat >> 4, seg = flat & 15;
        u64x2 val;
        val[0] = obuf[n][seg * 2];
        val[1] = obuf[n][seg * 2 + 1];
        *(u64x2*)&AOT[((size_t)g * HW + nb + n) * 128 + seg * 8] = val;
    }
}

extern "C" void kernel_launch(void* const* d_in, const int* in_sizes, int n_in,
                              void* d_out, int out_size, void* d_ws, size_t ws_size,
                              hipStream_t stream)
{
    (void)in_sizes; (void)n_in; (void)out_size; (void)ws_size;
    const float* x      = (const float*)d_in[0];
    const float* cv1_w  = (const float*)d_in[1];
    const float* cv1_g  = (const float*)d_in[2];
    const float* cv1_b  = (const float*)d_in[3];
    const float* cv1_m  = (const float*)d_in[4];
    const float* cv1_v  = (const float*)d_in[5];
    const float* n1_g   = (const float*)d_in[6];
    const float* n1_b   = (const float*)d_in[7];
    const float* qkv_w  = (const float*)d_in[8];
    const float* qkv_b  = (const float*)d_in[9];
    const float* proj_w = (const float*)d_in[10];
    const float* proj_b = (const float*)d_in[11];
    const float* n2_g   = (const float*)d_in[12];
    const float* n2_b   = (const float*)d_in[13];
    const float* f1_w   = (const float*)d_in[14];
    const float* f1_b   = (const float*)d_in[15];
    const float* f2_w   = (const float*)d_in[16];
    const float* f2_b   = (const float*)d_in[17];
    const float* cv2_w  = (const float*)d_in[18];
    const float* cv2_g  = (const float*)d_in[19];
    const float* cv2_b  = (const float*)d_in[20];
    const float* cv2_m  = (const float*)d_in[21];
    const float* cv2_v  = (const float*)d_in[22];
    float* out = (float*)d_out;

    float* ws = (float*)d_ws;
    ushort* CATT = (ushort*)ws;                      // [3][HW][512] bf16
    ushort* QT   = (ushort*)(ws + 1769472);          // [12][HW][32]
    ushort* KTb  = (ushort*)(ws + 2211840);          // [12][HW][32]
    ushort* VB   = (ushort*)(ws + 2654208);          // [384][HW]
    float*  MS   = ws + 3096576;                     // [4][12][HW][2]
    ushort* AOT  = (ushort*)(ws + 3317760);          // [3][HW][128]
    ushort* WB   = (ushort*)(ws + 3760128);          // 294912 bf16: cv1|proj|f2|cv2
    ushort* FW   = (ushort*)(ws + 3907584);          // 163840 bf16 folded qkv|f1
    float*  CV   = ws + 3989504;                     // 2560 f corrections
    float*  STAT = ws + 3992064;                     // 512 f
    float*  PO2  = ws + 3992576;                     // 884736 f
    float*  PO3  = PO2 + 884736;
    ushort* FT   = QT;                               // [3][HW][256] alias (QT+KT region)
    ushort* XTX  = (ushort*)PO2;                     // [3][HW][256] alias (dead after cv1)
    float*  PO0  = (float*)d_out;                    // [12][32][HW]
    float*  PO1  = PO0 + 884736;

    dim3 blk(256);

    cvt_w<<<dim3(288), blk, 0, stream>>>(cv1_w, proj_w, f2_w, cv2_w, WB);
    fold_w<<<dim3(5), blk, 0, stream>>>(qkv_w, n1_g, n1_b, f1_w, n2_g, n2_b, FW, CV);
    txp_x<<<dim3(36, 4, 3), blk, 0, stream>>>(x, XTX);

    // cv1: BN+SiLU -> CATT cols 0..255
    gemm_mfma<E_CV1><<<dim3(18, 2, 3), blk, 0, stream>>>(
        WB + 0, XTX, 256, 256, 0, cv1_g, cv1_b, cv1_m, cv1_v,
        nullptr, nullptr, CATT, 0, 0, nullptr, nullptr, nullptr, nullptr);

    for (int i = 0; i < 2; i++) {
        const int prev = (i == 0) ? 128 : 256;
        const int next = 256 + 128 * i;

        gn_partial<<<dim3(48, 3), blk, 0, stream>>>(CATT, prev, STAT);
        gn_reduce<<<dim3(3), dim3(64), 0, stream>>>(STAT);
        gemm_mfma<E_QKV><<<dim3(18, 3, 3), blk, 0, stream>>>(
            FW + (size_t)i * 49152, CATT, 128, 512, prev, qkv_b + i * 384,
            nullptr, nullptr, nullptr, STAT, CV + i * 1280,
            nullptr, 0, 0, nullptr, QT, KTb, VB);
        attn_mfma<<<dim3(36, 12, 4), blk, 0, stream>>>(QT, KTb, VB, PO0, PO1, PO2, PO3, MS);
        attn_merge<<<dim3(36, 3), blk, 0, stream>>>(PO0, PO1, PO2, PO3, MS, AOT);
        gemm_mfma<E_RES><<<dim3(18, 1, 3), blk, 0, stream>>>(
            WB + 65536 + (size_t)i * 16384, AOT, 128, 128, 0, proj_b + i * 128,
            nullptr, nullptr, nullptr, nullptr, nullptr,
            CATT, prev, next, nullptr, nullptr, nullptr, nullptr);

        gn_partial<<<dim3(48, 3), blk, 0, stream>>>(CATT, next, STAT);
        gn_reduce<<<dim3(3), dim3(64), 0, stream>>>(STAT);
        gemm_mfma<E_F1><<<dim3(18, 2, 3), blk, 0, stream>>>(
            FW + 98304 + (size_t)i * 32768, CATT, 128, 512, next, f1_b + i * 256,
            nullptr, nullptr, nullptr, STAT, CV + i * 1280 + 768,
            nullptr, 0, 0, nullptr, FT, nullptr, nullptr);
        gemm_mfma<E_RES><<<dim3(18, 1, 3), blk, 0, stream>>>(
            WB + 98304 + (size_t)i * 32768, FT, 256, 256, 0, f2_b + i * 128,
            nullptr, nullptr, nullptr, nullptr, nullptr,
            CATT, next, next, nullptr, nullptr, nullptr, nullptr);
    }

    // cv2: 256ch <- 512ch concat, BN+SiLU -> out
    gemm_mfma<E_CV2><<<dim3(18, 2, 3), blk, 0, stream>>>(
        WB + 163840, CATT, 512, 512, 0, cv2_g, cv2_b, cv2_m, cv2_v,
        nullptr, nullptr, nullptr, 0, 0, out, nullptr, nullptr, nullptr);
}

// Round 7
// 232.371 us; speedup vs baseline: 1.4077x; 1.0571x over previous
//
#include <hip/hip_runtime.h>
#include <hip/hip_bf16.h>
#include <math.h>

#define HW 2304
#define EPSV 1e-5f
#define INV_N (1.f / 294912.f)
// ATT_SCALE * log2(e): softmax runs in exp2 domain
#define QS_LOG2E (0.17677669529663687f * 1.44269504088896340f)

enum { E_CV1 = 0, E_QKV = 1, E_RES = 2, E_F1 = 3, E_CV2 = 4 };

typedef __attribute__((ext_vector_type(8))) short bf16x8;
typedef __attribute__((ext_vector_type(4))) float f32x4;

static __device__ __forceinline__ ushort b16(float f) {
    union { __hip_bfloat16 h; ushort u; } cv;
    cv.h = __float2bfloat16(f);
    return cv.u;
}
static __device__ __forceinline__ float bf(ushort u) {
    union { unsigned u; float f; } c; c.u = (unsigned)u << 16; return c.f;
}
// wave-reduce then 2 atomicAdds into STAT slot
static __device__ __forceinline__ void stat_acc(float* STAT, int slot, int b,
                                                float s, float sq) {
    #pragma unroll
    for (int off = 32; off; off >>= 1) { s += __shfl_xor(s, off); sq += __shfl_xor(sq, off); }
    if ((threadIdx.x & 63) == 0) {
        atomicAdd(&STAT[(slot * 3 + b) * 2], s);
        atomicAdd(&STAT[(slot * 3 + b) * 2 + 1], sq);
    }
}

// ---- prep: weight cvt + GN-fold + x transpose + STAT zero, one dispatch ----
// blocks [0,288): cvt_w; [288,293): fold_w; [293,725): txp_x.
__global__ __launch_bounds__(256) void prep(
    const float* __restrict__ cv1w, const float* __restrict__ projw,
    const float* __restrict__ f2w, const float* __restrict__ cv2w,
    const float* __restrict__ qw, const float* __restrict__ g1, const float* __restrict__ b1,
    const float* __restrict__ fw1, const float* __restrict__ g2, const float* __restrict__ b2,
    const float* __restrict__ X,
    ushort* __restrict__ WB, ushort* __restrict__ FW, float* __restrict__ CV,
    ushort* __restrict__ XT, float* __restrict__ STAT)
{
    __shared__ ushort tb[64][68];
    const int bid = blockIdx.x, t = threadIdx.x;
    if (bid < 288) {
        if (bid == 0 && t < 32) STAT[t] = 0.f;
        const int idx = (bid * 256 + t) * 4;  // < 294912
        const float* src;
        int off;
        if      (idx < 65536)  { src = cv1w; off = 0; }
        else if (idx < 98304)  { src = projw; off = 65536; }
        else if (idx < 163840) { src = f2w;  off = 98304; }
        else                   { src = cv2w; off = 163840; }
        float4 v = *(const float4*)&src[idx - off];
        ushort4 u;
        u.x = b16(v.x); u.y = b16(v.y); u.z = b16(v.z); u.w = b16(v.w);
        *(ushort4*)&WB[idx] = u;
    } else if (bid < 293) {
        const int idx = (bid - 288) * 256 + t;  // < 1280
        if (idx >= 1280) return;
        const int i = idx / 640, r = idx % 640;
        float sw = 0.f, wb = 0.f;
        if (r < 384) {
            const float* wrow = qw + ((size_t)i * 384 + r) * 128;
            const float* gg = g1 + i * 128;
            const float* bb = b1 + i * 128;
            ushort* dst = FW + (size_t)i * 49152 + r * 128;
            for (int c = 0; c < 128; c++) {
                const float w = wrow[c], wp = w * gg[c];
                dst[c] = b16(wp); sw += wp; wb += w * bb[c];
            }
            CV[i * 1280 + r] = sw;
            CV[i * 1280 + 384 + r] = wb;
        } else {
            const int o = r - 384;
            const float* wrow = fw1 + ((size_t)i * 256 + o) * 128;
            const float* gg = g2 + i * 128;
            const float* bb = b2 + i * 128;
            ushort* dst = FW + 98304 + (size_t)i * 32768 + o * 128;
            for (int c = 0; c < 128; c++) {
                const float w = wrow[c], wp = w * gg[c];
                dst[c] = b16(wp); sw += wp; wb += w * bb[c];
            }
            CV[i * 1280 + 768 + o] = sw;
            CV[i * 1280 + 1024 + o] = wb;
        }
    } else {
        const int flat = bid - 293;                 // < 432
        const int bx = flat % 36, by = (flat / 36) % 4, bz = flat / 144;
        const int cb = by * 64, nb = bx * 64;
        #pragma unroll
        for (int k = 0; k < 4; k++) {
            const int row = k * 16 + (t >> 4), cq = t & 15;
            float4 v = *(const float4*)&X[(size_t)(bz * 256 + cb + row) * HW + nb + cq * 4];
            ushort4 u; u.x = b16(v.x); u.y = b16(v.y); u.z = b16(v.z); u.w = b16(v.w);
            *(ushort4*)&tb[row][cq * 4] = u;
        }
        __syncthreads();
        #pragma unroll
        for (int k = 0; k < 4; k++) {
            const int n = k * 16 + (t >> 4), cq = t & 15;
            ushort4 u;
            u.x = tb[cq * 4 + 0][n]; u.y = tb[cq * 4 + 1][n];
            u.z = tb[cq * 4 + 2][n]; u.w = tb[cq * 4 + 3][n];
            *(ushort4*)&XT[((size_t)bz * HW + nb + n) * 256 + cb + cq * 4] = u;
        }
    }
}

// ---- MFMA GEMM: D[o][n] = sum_c W[o][c] * X[n][xoff+c], per batch b ----
template <int EPI>
__global__ __launch_bounds__(256) void gemm_mfma(
    const ushort* __restrict__ W, const ushort* __restrict__ X,
    int K, int xld, int xoff,
    const float* __restrict__ q0, const float* __restrict__ q1,
    const float* __restrict__ q2, const float* __restrict__ q3,
    float* __restrict__ STAT, int slotUse, int slotAcc,
    const float* __restrict__ cvec,
    ushort* __restrict__ CT, int rcol, int ycol,
    float* __restrict__ Yf,
    ushort* __restrict__ U0, ushort* __restrict__ U1, ushort* __restrict__ U2)
{
    const int b = blockIdx.z;
    const int t = threadIdx.x;
    const int w = t >> 6, l = t & 63;
    const int ln = l & 15, lg = l >> 4;
    const int wo = (w & 1) * 64, wn = (w >> 1) * 64;
    const int ob = blockIdx.y * 128 + wo;
    const int nb = blockIdx.x * 128 + wn;

    const ushort* ap = W + (size_t)(ob + ln) * K + lg * 8;
    const ushort* bp = X + ((size_t)b * HW + nb + ln) * xld + xoff + lg * 8;

    bf16x8 a0[4], bb0[4], a1[4], bb1[4];
    #pragma unroll
    for (int i = 0; i < 4; i++) {
        a0[i]  = *(const bf16x8*)(ap + (size_t)i * 16 * K);
        bb0[i] = *(const bf16x8*)(bp + (size_t)i * 16 * xld);
    }
    f32x4 acc[4][4];
    #pragma unroll
    for (int i = 0; i < 4; i++)
        #pragma unroll
        for (int j = 0; j < 4; j++) acc[i][j] = (f32x4){0.f, 0.f, 0.f, 0.f};

    for (int c0 = 32; c0 <= K; c0 += 32) {
        if (c0 < K) {
            #pragma unroll
            for (int i = 0; i < 4; i++) {
                a1[i]  = *(const bf16x8*)(ap + (size_t)i * 16 * K + c0);
                bb1[i] = *(const bf16x8*)(bp + (size_t)i * 16 * xld + c0);
            }
        }
        #pragma unroll
        for (int i = 0; i < 4; i++)
            #pragma unroll
            for (int j = 0; j < 4; j++)
                acc[i][j] = __builtin_amdgcn_mfma_f32_16x16x32_bf16(a0[i], bb0[j], acc[i][j], 0, 0, 0);
        #pragma unroll
        for (int i = 0; i < 4; i++) { a0[i] = a1[i]; bb0[i] = bb1[i]; }
    }

    float mu = 0.f, rs = 0.f;
    if (EPI == E_QKV || EPI == E_F1) {
        const float s  = STAT[(slotUse * 3 + b) * 2];
        const float sq = STAT[(slotUse * 3 + b) * 2 + 1];
        mu = s * INV_N;
        rs = rsqrtf(sq * INV_N - mu * mu + EPSV);
    }
    float ls = 0.f, lsq = 0.f;

    #pragma unroll
    for (int i = 0; i < 4; i++) {
        const int obase = ob + i * 16 + lg * 4;   // 4 consecutive o (r=0..3)
        if (EPI == E_CV1 || EPI == E_CV2) {
            float sc[4], sh[4];
            #pragma unroll
            for (int r = 0; r < 4; r++) {
                const int o = obase + r;
                const float irs = rsqrtf(q3[o] + EPSV);
                sc[r] = q0[o] * irs;
                sh[r] = q1[o] - q2[o] * sc[r];
            }
            #pragma unroll
            for (int j = 0; j < 4; j++) {
                const int n = nb + j * 16 + ln;
                ushort4 u;
                #pragma unroll
                for (int r = 0; r < 4; r++) {
                    float y = fmaf(acc[i][j][r], sc[r], sh[r]);
                    y = y / (1.f + __expf(-y));
                    if (EPI == E_CV2) {
                        Yf[(size_t)(b * 256 + obase + r) * HW + n] = y;
                    } else {
                        ls += y; lsq += y * y;
                        if (r == 0) u.x = b16(y); else if (r == 1) u.y = b16(y);
                        else if (r == 2) u.z = b16(y); else u.w = b16(y);
                    }
                }
                if (EPI == E_CV1)
                    *(ushort4*)&CT[((size_t)b * HW + n) * 512 + ycol + obase] = u;
            }
        } else if (EPI == E_QKV) {
            // Q = batch0's 384ch, K = batch1's, V = batch2's (reference quirk).
            const int gh = obase >> 5;   // chunk*4 + head
            const int d0 = obase & 31;
            float C[4];
            #pragma unroll
            for (int r = 0; r < 4; r++) {
                const int o = obase + r;
                C[r] = q0[o] + cvec[384 + o] - rs * mu * cvec[o];
            }
            #pragma unroll
            for (int j = 0; j < 4; j++) {
                const int n = nb + j * 16 + ln;
                float y0 = fmaf(rs, acc[i][j][0], C[0]);
                float y1 = fmaf(rs, acc[i][j][1], C[1]);
                float y2 = fmaf(rs, acc[i][j][2], C[2]);
                float y3 = fmaf(rs, acc[i][j][3], C[3]);
                if (b == 0) {
                    ushort4 u;
                    u.x = b16(y0 * QS_LOG2E); u.y = b16(y1 * QS_LOG2E);
                    u.z = b16(y2 * QS_LOG2E); u.w = b16(y3 * QS_LOG2E);
                    *(ushort4*)&U0[((size_t)gh * HW + n) * 32 + d0] = u;
                } else if (b == 1) {
                    ushort4 u;
                    u.x = b16(y0); u.y = b16(y1); u.z = b16(y2); u.w = b16(y3);
                    *(ushort4*)&U1[((size_t)gh * HW + n) * 32 + d0] = u;
                } else {
                    U2[(size_t)(obase + 0) * HW + n] = b16(y0);
                    U2[(size_t)(obase + 1) * HW + n] = b16(y1);
                    U2[(size_t)(obase + 2) * HW + n] = b16(y2);
                    U2[(size_t)(obase + 3) * HW + n] = b16(y3);
                }
            }
        } else if (EPI == E_RES) {
            #pragma unroll
            for (int j = 0; j < 4; j++) {
                const int n = nb + j * 16 + ln;
                const size_t base = ((size_t)b * HW + n) * 512;
                ushort4 rv = *(const ushort4*)&CT[base + rcol + obase];
                float y0 = acc[i][j][0] + q0[obase + 0] + bf(rv.x);
                float y1 = acc[i][j][1] + q0[obase + 1] + bf(rv.y);
                float y2 = acc[i][j][2] + q0[obase + 2] + bf(rv.z);
                float y3 = acc[i][j][3] + q0[obase + 3] + bf(rv.w);
                ls += (y0 + y1) + (y2 + y3);
                lsq += y0 * y0 + y1 * y1 + y2 * y2 + y3 * y3;
                ushort4 u;
                u.x = b16(y0); u.y = b16(y1); u.z = b16(y2); u.w = b16(y3);
                *(ushort4*)&CT[base + ycol + obase] = u;
            }
        } else {  // E_F1: gelu(rs*acc + C) -> FT bf16 [b][n][256]
            float C[4];
            #pragma unroll
            for (int r = 0; r < 4; r++) {
                const int o = obase + r;
                C[r] = q0[o] + cvec[256 + o] - rs * mu * cvec[o];
            }
            #pragma unroll
            for (int j = 0; j < 4; j++) {
                const int n = nb + j * 16 + ln;
                ushort4 u;
                #pragma unroll
                for (int r = 0; r < 4; r++) {
                    float y = fmaf(rs, acc[i][j][r], C[r]);
                    y = 0.5f * y * (1.f + erff(y * 0.70710678f));
                    if (r == 0) u.x = b16(y); else if (r == 1) u.y = b16(y);
                    else if (r == 2) u.z = b16(y); else u.w = b16(y);
                }
                *(ushort4*)&U0[((size_t)b * HW + n) * 256 + obase] = u;
            }
        }
    }
    if (EPI == E_CV1 && slotAcc >= 0 && blockIdx.y == 1) stat_acc(STAT, slotAcc, b, ls, lsq);
    if (EPI == E_RES && slotAcc >= 0) stat_acc(STAT, slotAcc, b, ls, lsq);
}

// ---- MFMA flash attention, split-K=4, LDS-staged K/V shared by 4 waves ----
// grid (36, 12, 4); 256 threads = 4 waves, each 16 queries; 64-key tiles.
__global__ __launch_bounds__(256) void attn_mfma(
    const ushort* __restrict__ QT,  // [12][HW][32] bf16, pre-scaled by QS_LOG2E
    const ushort* __restrict__ KT,  // [12][HW][32] bf16
    const ushort* __restrict__ VB,  // [384][HW] bf16
    float* __restrict__ PO0, float* __restrict__ PO1,
    float* __restrict__ PO2, float* __restrict__ PO3,
    float* __restrict__ MS)         // [4][12][HW][2]
{
    __shared__ __align__(16) ushort Kl[2][2048];
    __shared__ __align__(16) ushort Vl[2][2048];
    __shared__ __align__(16) ushort plds[4][16][72];
    const int gh = blockIdx.y, g = gh >> 2, h = gh & 3;
    const int half = blockIdx.z;
    const int t = threadIdx.x, w = t >> 6, l = t & 63;
    const int ln = l & 15, lg = l >> 4;
    const int n0 = (blockIdx.x * 4 + w) * 16;
    const int ms0 = half * 576, mend = ms0 + 576;

    const ushort* ktg = KT + (size_t)gh * HW * 32;
    const ushort* vg  = VB + ((size_t)g * 128 + h * 32) * HW;

    const int krow = t >> 2, kcq = t & 3;
    const int vrow = t >> 3, vcq = t & 7;
    const int kw = krow * 32 + ((kcq ^ (krow & 3)) << 3);
    const int vw = vrow * 64 + ((vcq ^ (vrow & 7)) << 3);
    const int krd = ln * 32 + ((lg ^ (ln & 3)) << 3);
    const int vs  = ln & 7;
    const int vrd0 = ln * 64 + ((lg ^ vs) << 3);
    const int vrd1 = ln * 64 + (((lg + 4) ^ vs) << 3);
    const int vrd2 = (16 + ln) * 64 + ((lg ^ vs) << 3);
    const int vrd3 = (16 + ln) * 64 + (((lg + 4) ^ vs) << 3);

    const bf16x8 qf = *(const bf16x8*)(QT + ((size_t)gh * HW + n0 + ln) * 32 + lg * 8);

    f32x4 o0 = {0.f, 0.f, 0.f, 0.f}, o1 = {0.f, 0.f, 0.f, 0.f};
    float M = -3.0e38f, S = 0.f;

    {
        bf16x8 kr = *(const bf16x8*)(ktg + (size_t)(ms0 + krow) * 32 + kcq * 8);
        bf16x8 vr = *(const bf16x8*)(vg + (size_t)vrow * HW + ms0 + vcq * 8);
        *(bf16x8*)&Kl[0][kw] = kr;
        *(bf16x8*)&Vl[0][vw] = vr;
    }
    int cur = 0;

    for (int m0 = ms0; m0 < mend; m0 += 64) {
        __syncthreads();
        const bool more = (m0 + 64 < mend);
        bf16x8 kr, vr;
        if (more) {
            kr = *(const bf16x8*)(ktg + (size_t)(m0 + 64 + krow) * 32 + kcq * 8);
            vr = *(const bf16x8*)(vg + (size_t)vrow * HW + m0 + 64 + vcq * 8);
        }

        f32x4 st[4];
        const f32x4 zero = {0.f, 0.f, 0.f, 0.f};
        #pragma unroll
        for (int mc = 0; mc < 4; mc++) {
            const bf16x8 kf = *(const bf16x8*)&Kl[cur][mc * 512 + krd];
            st[mc] = __builtin_amdgcn_mfma_f32_16x16x32_bf16(kf, qf, zero, 0, 0, 0);
        }

        float mx = st[0][0];
        #pragma unroll
        for (int mc = 0; mc < 4; mc++)
            #pragma unroll
            for (int r = 0; r < 4; r++) mx = fmaxf(mx, st[mc][r]);
        mx = fmaxf(mx, __shfl_xor(mx, 16));
        mx = fmaxf(mx, __shfl_xor(mx, 32));
        if (!__all(mx <= M + 8.f)) {
            const float Mn = fmaxf(M, mx);
            const float corr = exp2f(M - Mn);
            S *= corr;
            #pragma unroll
            for (int r = 0; r < 4; r++) { o0[r] *= corr; o1[r] *= corr; }
            M = Mn;
        }
        float ps = 0.f;
        ushort4 pw[4];
        #pragma unroll
        for (int mc = 0; mc < 4; mc++) {
            float p0v = exp2f(st[mc][0] - M), p1v = exp2f(st[mc][1] - M);
            float p2v = exp2f(st[mc][2] - M), p3v = exp2f(st[mc][3] - M);
            ps += (p0v + p1v) + (p2v + p3v);
            pw[mc].x = b16(p0v); pw[mc].y = b16(p1v);
            pw[mc].z = b16(p2v); pw[mc].w = b16(p3v);
        }
        ps += __shfl_xor(ps, 16);
        ps += __shfl_xor(ps, 32);
        S += ps;

        #pragma unroll
        for (int mc = 0; mc < 4; mc++)
            *(ushort4*)&plds[w][ln][mc * 16 + lg * 4] = pw[mc];
        bf16x8 pf0 = *(const bf16x8*)&plds[w][ln][lg * 8];
        bf16x8 pf1 = *(const bf16x8*)&plds[w][ln][32 + lg * 8];

        const bf16x8 vf0 = *(const bf16x8*)&Vl[cur][vrd0];
        const bf16x8 vf1 = *(const bf16x8*)&Vl[cur][vrd1];
        const bf16x8 vf2 = *(const bf16x8*)&Vl[cur][vrd2];
        const bf16x8 vf3 = *(const bf16x8*)&Vl[cur][vrd3];
        o0 = __builtin_amdgcn_mfma_f32_16x16x32_bf16(vf0, pf0, o0, 0, 0, 0);
        o0 = __builtin_amdgcn_mfma_f32_16x16x32_bf16(vf1, pf1, o0, 0, 0, 0);
        o1 = __builtin_amdgcn_mfma_f32_16x16x32_bf16(vf2, pf0, o1, 0, 0, 0);
        o1 = __builtin_amdgcn_mfma_f32_16x16x32_bf16(vf3, pf1, o1, 0, 0, 0);

        if (more) {
            *(bf16x8*)&Kl[cur ^ 1][kw] = kr;
            *(bf16x8*)&Vl[cur ^ 1][vw] = vr;
        }
        cur ^= 1;
    }

    float* po = (half == 0) ? PO0 : (half == 1) ? PO1 : (half == 2) ? PO2 : PO3;
    #pragma unroll
    for (int r = 0; r < 4; r++) {
        const int d = lg * 4 + r;
        po[((size_t)gh * 32 + d) * HW + n0 + ln]      = o0[r];
        po[((size_t)gh * 32 + d + 16) * HW + n0 + ln] = o1[r];
    }
    if (lg == 0) {
        float* ms = MS + (((size_t)half * 12 + gh) * HW + n0 + ln) * 2;
        ms[0] = M; ms[1] = S;
    }
}

// ---- merge 4 split-K partials + proj GEMM + residual -> CATT[ycol] ----
// grid (36, 3); 256 threads = 4 waves.
__global__ __launch_bounds__(256) void merge_proj(
    const float* __restrict__ PO0, const float* __restrict__ PO1,
    const float* __restrict__ PO2, const float* __restrict__ PO3,
    const float* __restrict__ MS,
    const ushort* __restrict__ PW, const float* __restrict__ pb,
    ushort* __restrict__ CT, int rcol, int ycol,
    float* __restrict__ STAT, int slotAcc)
{
    __shared__ float fw[4][4][64];   // [h][half][nl]
    __shared__ __align__(16) unsigned long long obuf[64][34];  // [n][c/4], 272B rows
    const int g = blockIdx.y, nb = blockIdx.x * 64;
    const int t = threadIdx.x;
    {
        const int h = t >> 6, nl = t & 63, gh = g * 4 + h, n = nb + nl;
        float Mk[4], Sk[4];
        #pragma unroll
        for (int k = 0; k < 4; k++) {
            Mk[k] = MS[(((size_t)k * 12 + gh) * HW + n) * 2 + 0];
            Sk[k] = MS[(((size_t)k * 12 + gh) * HW + n) * 2 + 1];
        }
        const float Mx = fmaxf(fmaxf(Mk[0], Mk[1]), fmaxf(Mk[2], Mk[3]));
        float wk[4], den = 0.f;
        #pragma unroll
        for (int k = 0; k < 4; k++) { wk[k] = exp2f(Mk[k] - Mx); den += Sk[k] * wk[k]; }
        const float inv = 1.f / den;
        #pragma unroll
        for (int k = 0; k < 4; k++) fw[h][k][nl] = wk[k] * inv;
    }
    __syncthreads();
    {
        const int nl = t & 63, dd = t >> 6;
        #pragma unroll
        for (int p = 0; p < 8; p++) {
            const int d = p * 4 + dd;
            ushort uu[4];
            #pragma unroll
            for (int h = 0; h < 4; h++) {
                const int gh = g * 4 + h;
                const size_t idx = ((size_t)gh * 32 + d) * HW + nb + nl;
                const float v = PO0[idx] * fw[h][0][nl] + PO1[idx] * fw[h][1][nl]
                              + PO2[idx] * fw[h][2][nl] + PO3[idx] * fw[h][3][nl];
                uu[h] = b16(v);
            }
            obuf[nl][d] = (unsigned long long)uu[0] | ((unsigned long long)uu[1] << 16)
                        | ((unsigned long long)uu[2] << 32) | ((unsigned long long)uu[3] << 48);
        }
    }
    __syncthreads();
    // proj: y[o][n] = sum_c PW[o][c]*obuf[n][c], o<128, n<64 (c = d*4+h)
    const int w = t >> 6, l = t & 63, ln = l & 15, lg = l >> 4;
    const int wo = (w & 1) * 64, wn = (w >> 1) * 32;
    const ushort* ob_base = (const ushort*)&obuf[0][0];  // row stride 136 ushorts
    const ushort* ap = PW + (size_t)(wo + ln) * 128 + lg * 8;
    f32x4 acc[4][2];
    #pragma unroll
    for (int i = 0; i < 4; i++)
        #pragma unroll
        for (int jf = 0; jf < 2; jf++) acc[i][jf] = (f32x4){0.f, 0.f, 0.f, 0.f};
    #pragma unroll
    for (int kk = 0; kk < 4; kk++) {
        bf16x8 bfr[2];
        #pragma unroll
        for (int jf = 0; jf < 2; jf++)
            bfr[jf] = *(const bf16x8*)(ob_base + (wn + jf * 16 + ln) * 136 + kk * 32 + lg * 8);
        #pragma unroll
        for (int i = 0; i < 4; i++) {
            const bf16x8 af = *(const bf16x8*)(ap + (size_t)i * 16 * 128 + kk * 32);
            acc[i][0] = __builtin_amdgcn_mfma_f32_16x16x32_bf16(af, bfr[0], acc[i][0], 0, 0, 0);
            acc[i][1] = __builtin_amdgcn_mfma_f32_16x16x32_bf16(af, bfr[1], acc[i][1], 0, 0, 0);
        }
    }
    float ls = 0.f, lsq = 0.f;
    #pragma unroll
    for (int i = 0; i < 4; i++) {
        const int o4 = wo + i * 16 + lg * 4;
        #pragma unroll
        for (int jf = 0; jf < 2; jf++) {
            const int n = nb + wn + jf * 16 + ln;
            const size_t base = ((size_t)g * HW + n) * 512;
            ushort4 rv = *(const ushort4*)&CT[base + rcol + o4];
            float y0 = acc[i][jf][0] + pb[o4 + 0] + bf(rv.x);
            float y1 = acc[i][jf][1] + pb[o4 + 1] + bf(rv.y);
            float y2 = acc[i][jf][2] + pb[o4 + 2] + bf(rv.z);
            float y3 = acc[i][jf][3] + pb[o4 + 3] + bf(rv.w);
            ls += (y0 + y1) + (y2 + y3);
            lsq += y0 * y0 + y1 * y1 + y2 * y2 + y3 * y3;
            ushort4 u;
            u.x = b16(y0); u.y = b16(y1); u.z = b16(y2); u.w = b16(y3);
            *(ushort4*)&CT[base + ycol + o4] = u;
        }
    }
    stat_acc(STAT, slotAcc, g, ls, lsq);
}

extern "C" void kernel_launch(void* const* d_in, const int* in_sizes, int n_in,
                              void* d_out, int out_size, void* d_ws, size_t ws_size,
                              hipStream_t stream)
{
    (void)in_sizes; (void)n_in; (void)out_size; (void)ws_size;
    const float* x      = (const float*)d_in[0];
    const float* cv1_w  = (const float*)d_in[1];
    const float* cv1_g  = (const float*)d_in[2];
    const float* cv1_b  = (const float*)d_in[3];
    const float* cv1_m  = (const float*)d_in[4];
    const float* cv1_v  = (const float*)d_in[5];
    const float* n1_g   = (const float*)d_in[6];
    const float* n1_b   = (const float*)d_in[7];
    const float* qkv_w  = (const float*)d_in[8];
    const float* qkv_b  = (const float*)d_in[9];
    const float* proj_w = (const float*)d_in[10];
    const float* proj_b = (const float*)d_in[11];
    const float* n2_g   = (const float*)d_in[12];
    const float* n2_b   = (const float*)d_in[13];
    const float* f1_w   = (const float*)d_in[14];
    const float* f1_b   = (const float*)d_in[15];
    const float* f2_w   = (const float*)d_in[16];
    const float* f2_b   = (const float*)d_in[17];
    const float* cv2_w  = (const float*)d_in[18];
    const float* cv2_g  = (const float*)d_in[19];
    const float* cv2_b  = (const float*)d_in[20];
    const float* cv2_m  = (const float*)d_in[21];
    const float* cv2_v  = (const float*)d_in[22];
    float* out = (float*)d_out;

    float* ws = (float*)d_ws;
    ushort* CATT = (ushort*)ws;                      // [3][HW][512] bf16
    ushort* QT   = (ushort*)(ws + 1769472);          // [12][HW][32]
    ushort* KTb  = (ushort*)(ws + 2211840);          // [12][HW][32]
    ushort* VB   = (ushort*)(ws + 2654208);          // [384][HW]
    float*  MS   = ws + 3096576;                     // [4][12][HW][2]
    ushort* WB   = (ushort*)(ws + 3317760);          // 294912 bf16: cv1|proj|f2|cv2
    ushort* FW   = (ushort*)(ws + 3465216);          // 163840 bf16 folded qkv|f1
    float*  CV   = ws + 3547136;                     // 2560 f corrections
    float*  STAT = ws + 3549696;                     // 32 f (4 slots x 3 b x 2)
    float*  PO2  = ws + 3549760;                     // 884736 f
    float*  PO3  = PO2 + 884736;
    ushort* FT   = QT;                               // [3][HW][256] alias (QT+KT region)
    ushort* XTX  = (ushort*)PO2;                     // [3][HW][256] alias (dead after cv1)
    float*  PO0  = (float*)d_out;                    // [12][32][HW]
    float*  PO1  = PO0 + 884736;

    dim3 blk(256);

    prep<<<dim3(725), blk, 0, stream>>>(
        cv1_w, proj_w, f2_w, cv2_w, qkv_w, n1_g, n1_b, f1_w, n2_g, n2_b,
        x, WB, FW, CV, XTX, STAT);

    // cv1: BN+SiLU -> CATT cols 0..255; stats(slot0) over cols 128..255
    gemm_mfma<E_CV1><<<dim3(18, 2, 3), blk, 0, stream>>>(
        WB + 0, XTX, 256, 256, 0, cv1_g, cv1_b, cv1_m, cv1_v,
        STAT, -1, 0, nullptr, CATT, 0, 0, nullptr, nullptr, nullptr, nullptr);

    for (int i = 0; i < 2; i++) {
        const int prev = (i == 0) ? 128 : 256;
        const int next = 256 + 128 * i;
        const int gn1 = (i == 0) ? 0 : 2;   // stats slot consumed by qkv
        const int gn2 = (i == 0) ? 1 : 3;   // stats slot consumed by f1

        gemm_mfma<E_QKV><<<dim3(18, 3, 3), blk, 0, stream>>>(
            FW + (size_t)i * 49152, CATT, 128, 512, prev, qkv_b + i * 384,
            nullptr, nullptr, nullptr, STAT, gn1, -1, CV + i * 1280,
            nullptr, 0, 0, nullptr, QT, KTb, VB);
        attn_mfma<<<dim3(36, 12, 4), blk, 0, stream>>>(QT, KTb, VB, PO0, PO1, PO2, PO3, MS);
        merge_proj<<<dim3(36, 3), blk, 0, stream>>>(
            PO0, PO1, PO2, PO3, MS, WB + 65536 + (size_t)i * 16384, proj_b + i * 128,
            CATT, prev, next, STAT, gn2);

        gemm_mfma<E_F1><<<dim3(18, 2, 3), blk, 0, stream>>>(
            FW + 98304 + (size_t)i * 32768, CATT, 128, 512, next, f1_b + i * 256,
            nullptr, nullptr, nullptr, STAT, gn2, -1, CV + i * 1280 + 768,
            nullptr, 0, 0, nullptr, FT, nullptr, nullptr);
        gemm_mfma<E_RES><<<dim3(18, 1, 3), blk, 0, stream>>>(
            WB + 98304 + (size_t)i * 32768, FT, 256, 256, 0, f2_b + i * 128,
            nullptr, nullptr, nullptr, STAT, -1, (i == 0) ? 2 : -1, nullptr,
            CATT, next, next, nullptr, nullptr, nullptr, nullptr);
    }

    // cv2: 256ch <- 512ch concat, BN+SiLU -> out
    gemm_mfma<E_CV2><<<dim3(18, 2, 3), blk, 0, stream>>>(
        WB + 163840, CATT, 512, 512, 0, cv2_g, cv2_b, cv2_m, cv2_v,
        STAT, -1, -1, nullptr, nullptr, 0, 0, out, nullptr, nullptr, nullptr);
}